// Round 10
// baseline (220.253 us; speedup 1.0000x reference)
//
#include <hip/hip_runtime.h>

typedef __bf16 bf16x8 __attribute__((ext_vector_type(8)));
typedef __bf16 bf16x4 __attribute__((ext_vector_type(4)));
typedef float f32x4 __attribute__((ext_vector_type(4)));
typedef unsigned short u16;
typedef unsigned int u32;
typedef u32 u32x4 __attribute__((ext_vector_type(4)));

// round-to-nearest-even f32 -> bf16
__device__ __forceinline__ u16 f2bf(float f) {
  u32 u = __builtin_bit_cast(u32, f);
  u += 0x7fffu + ((u >> 16) & 1u);
  return (u16)(u >> 16);
}

// packed f32x2 -> bf16x2 (RNE); low u16 = first arg (verified R2/R4)
__device__ __forceinline__ u32 cvt_pk_bf16(float lo, float hi) {
  u32 r;
  asm("v_cvt_pk_bf16_f32 %0, %1, %2" : "=v"(r) : "v"(lo), "v"(hi));
  return r;
}

// raw v_exp_f32: r = 2^x (scores pre-scaled to log2 domain)
__device__ __forceinline__ float ex2(float x) {
  float r;
  asm("v_exp_f32 %0, %1" : "=v"(r) : "v"(x));
  return r;
}

// async global->LDS, 16B per lane. LDS dest = wave-uniform base (HW adds lane*16).
__device__ __forceinline__ void gl_lds16(const u16* g, u16* l) {
  __builtin_amdgcn_global_load_lds(
      (const __attribute__((address_space(1))) u32*)g,
      (__attribute__((address_space(3))) u32*)l, 16, 0, 0);
}

// LDS transpose read. Per-lane address REQUIRED: p = base + lane*4 (elems).
__device__ __forceinline__ bf16x4 tr16(const u16* p) {
  bf16x4 r;
  auto lp = (const __attribute__((address_space(3))) u16*)p;
  asm volatile("ds_read_b64_tr_b16 %0, %1" : "=&v"(r) : "v"(lp));
  return r;
}

// ---------------- cast x: f32 -> bf16, 8 elems/thread ----------------
__global__ __launch_bounds__(256) void k_cast(const float* __restrict__ in,
                                              u16* __restrict__ out, int n8) {
  int i = blockIdx.x * 256 + threadIdx.x;
  if (i >= n8) return;
  const float4* p = (const float4*)in + (size_t)i * 2;
  float4 a = p[0], b = p[1];
  u16 r[8] = {f2bf(a.x), f2bf(a.y), f2bf(a.z), f2bf(a.w),
              f2bf(b.x), f2bf(b.y), f2bf(b.z), f2bf(b.w)};
  ((uint4*)out)[i] = *(const uint4*)r;
}

// ---------- transpose+cast: W [K][N] f32 -> Wt [N][K] bf16 ----------
__global__ __launch_bounds__(256) void k_tcast(const float* __restrict__ in,
                                               u16* __restrict__ out, int K, int N) {
  __shared__ float tile[32][33];
  int n0 = blockIdx.x * 32, k0 = blockIdx.y * 32;
  int c = threadIdx.x & 31, r0 = (threadIdx.x >> 5) * 4;
#pragma unroll
  for (int rr = 0; rr < 4; ++rr) {
    int r = r0 + rr;
    tile[r][c] = in[(size_t)(k0 + r) * N + n0 + c];
  }
  __syncthreads();
#pragma unroll
  for (int rr = 0; rr < 4; ++rr) {
    int r = r0 + rr;
    out[(size_t)(n0 + r) * K + k0 + c] = f2bf(tile[c][r]);
  }
}

// ---------------- bf16 GEMM: C[M,N] = A[M,K] * Bt[N,K]^T ----------------
template <int EPI>
__global__ __launch_bounds__(256) void k_gemm(const u16* __restrict__ A,
                                              const u16* __restrict__ Bt,
                                              u16* __restrict__ Qp, u16* __restrict__ Kp,
                                              u16* __restrict__ Vp, float* __restrict__ Cf,
                                              int K) {
  __shared__ u16 As[128 * 32];
  __shared__ u16 Bs[128 * 32];
  const int tid = threadIdx.x;
  const int lane = tid & 63, wave = tid >> 6;
  const int l15 = lane & 15, l4 = lane >> 4;
  const int wr = wave >> 1, wc = wave & 1;
  const int tm = blockIdx.y, tn = blockIdx.x;

  int srow[2], scol[2];
#pragma unroll
  for (int i = 0; i < 2; ++i) {
    int row = (wave * 2 + i) * 16 + (lane >> 2);
    srow[i] = row;
    scol[i] = ((lane & 3) ^ ((row >> 1) & 3)) * 8;
  }

  const f32x4 fz = {0.f, 0.f, 0.f, 0.f};
  f32x4 acc[4][4];
#pragma unroll
  for (int a = 0; a < 4; ++a)
#pragma unroll
    for (int b = 0; b < 4; ++b) acc[a][b] = fz;

  const int nk = K >> 5;
  for (int kt = 0; kt < nk; ++kt) {
#pragma unroll
    for (int i = 0; i < 2; ++i) {
      gl_lds16(A + (size_t)(tm * 128 + srow[i]) * K + kt * 32 + scol[i],
               &As[(wave * 2 + i) * 512]);
      gl_lds16(Bt + (size_t)(tn * 128 + srow[i]) * K + kt * 32 + scol[i],
               &Bs[(wave * 2 + i) * 512]);
    }
    __syncthreads();
    bf16x8 af[4], bfr[4];
#pragma unroll
    for (int mi = 0; mi < 4; ++mi) {
      int row = wr * 64 + mi * 16 + l15;
      int pch = l4 ^ ((row >> 1) & 3);
      af[mi] = *(const bf16x8*)&As[row * 32 + pch * 8];
    }
#pragma unroll
    for (int ni = 0; ni < 4; ++ni) {
      int row = wc * 64 + ni * 16 + l15;
      int pch = l4 ^ ((row >> 1) & 3);
      bfr[ni] = *(const bf16x8*)&Bs[row * 32 + pch * 8];
    }
#pragma unroll
    for (int mi = 0; mi < 4; ++mi)
#pragma unroll
      for (int ni = 0; ni < 4; ++ni)
        acc[mi][ni] = __builtin_amdgcn_mfma_f32_16x16x32_bf16(af[mi], bfr[ni],
                                                              acc[mi][ni], 0, 0, 0);
    __syncthreads();
  }

  const int rbase = tm * 128 + wr * 64 + l4 * 4;
  const int cbase = tn * 128 + wc * 64 + l15;
  if (EPI == 0) {
#pragma unroll
    for (int ni = 0; ni < 4; ++ni) {
      int col = cbase + ni * 16;
      int which = col >> 10;
      int d = col & 1023;
      int h = d >> 6, hd = d & 63;
      u16* dst = which == 0 ? Qp : (which == 1 ? Kp : Vp);
      float scl = which == 0 ? 0.180336880f : 1.0f;  // 0.125 * log2(e)
#pragma unroll
      for (int mi = 0; mi < 4; ++mi) {
#pragma unroll
        for (int r = 0; r < 4; ++r) {
          int rowg = rbase + mi * 16 + r;
          int b = rowg >> 11, t = rowg & 2047;
          dst[(size_t)(((b * 16 + h) * 2048 + t) * 64 + hd)] = f2bf(acc[mi][ni][r] * scl);
        }
      }
    }
  } else {
#pragma unroll
    for (int mi = 0; mi < 4; ++mi)
#pragma unroll
      for (int r = 0; r < 4; ++r) {
        int rowg = rbase + mi * 16 + r;
#pragma unroll
        for (int ni = 0; ni < 4; ++ni)
          Cf[(size_t)rowg * 1024 + cbase + ni * 16] = acc[mi][ni][r];
      }
  }
}

// ---------------- causal flash attention (R8 structure, templated for ablation) ----
// VAR=0 full (real output); VAR=1 noSM; VAR=2 noPV; VAR=3 noQK.
// Ablation variants keep upstream values live (rule #17) and keep the staging /
// barrier skeleton identical; they write to dead scratch.
template <int VAR>
__global__ __launch_bounds__(256) void k_attn(const u16* __restrict__ Q,
                                              const u16* __restrict__ K,
                                              const u16* __restrict__ V,
                                              u16* __restrict__ Y) {
  __shared__ u16 Kl[3][64 * 64];
  __shared__ u16 Vtr[3][64 * 64];
  const int tid = threadIdx.x, lane = tid & 63, wave = tid >> 6;
  const int l15 = lane & 15, l4 = lane >> 4;
  const int bh = blockIdx.y;
  const int pp = (blockIdx.x + ((blockIdx.y >> 4) << 3)) & 15;
  const int qtA = 31 - pp, qtB = pp;
  const u16* Qb = Q + (size_t)bh * 2048 * 64;
  const u16* Kb = K + (size_t)bh * 2048 * 64;
  const u16* Vb = V + (size_t)bh * 2048 * 64;
  const int b = bh >> 4, h = bh & 15;
  const f32x4 fz = {0.f, 0.f, 0.f, 0.f};

  const int kk0 = wave * 16 + (lane >> 3);
  const int kk1 = kk0 + 8;
  const int lcol0 = ((lane & 7) ^ (kk0 & 7)) * 8;
  const int lcol1 = ((lane & 7) ^ (kk1 & 7)) * 8;
  int vk[2], vhd[2];
#pragma unroll
  for (int i = 0; i < 2; ++i) {
    int o = (wave * 2 + i) * 512 + lane * 8;
    vk[i] = ((o >> 6) & 15) * 4 + ((o >> 4) & 3);
    vhd[i] = ((o >> 10) << 4) + (o & 8);
  }

  auto stage = [&](int buf, int kt) {
    gl_lds16(Kb + (size_t)(kt * 64 + kk0) * 64 + lcol0, &Kl[buf][(wave * 2 + 0) * 512]);
    gl_lds16(Kb + (size_t)(kt * 64 + kk1) * 64 + lcol1, &Kl[buf][(wave * 2 + 1) * 512]);
    gl_lds16(Vb + (size_t)(kt * 64 + vk[0]) * 64 + vhd[0], &Vtr[buf][(wave * 2 + 0) * 512]);
    gl_lds16(Vb + (size_t)(kt * 64 + vk[1]) * 64 + vhd[1], &Vtr[buf][(wave * 2 + 1) * 512]);
  };

  bf16x8 qfA[2], qfB[2];
  {
    int qrA = qtA * 64 + wave * 16 + l15;
    int qrB = qtB * 64 + wave * 16 + l15;
    qfA[0] = *(const bf16x8*)&Qb[(size_t)qrA * 64 + l4 * 8];
    qfA[1] = *(const bf16x8*)&Qb[(size_t)qrA * 64 + 32 + l4 * 8];
    qfB[0] = *(const bf16x8*)&Qb[(size_t)qrB * 64 + l4 * 8];
    qfB[1] = *(const bf16x8*)&Qb[(size_t)qrB * 64 + 32 + l4 * 8];
  }
  f32x4 oA[4] = {fz, fz, fz, fz}, oB[4] = {fz, fz, fz, fz};
  float mA = -1e30f, lsA = 0.f, mB = -1e30f, lsB = 0.f;

  stage(0, 0);
  stage(1, 1);
  stage(2, 2);

  int cur = 0, kt = 0;

  // ======== phase 1: both tiles active ========
#pragma unroll 1
  for (; kt <= qtB; ++kt) {
    asm volatile("s_waitcnt vmcnt(8)" ::: "memory");
    __builtin_amdgcn_s_barrier();
    __builtin_amdgcn_sched_barrier(0);

    f32x4 sA[4] = {fz, fz, fz, fz}, sB[4] = {fz, fz, fz, fz};
    if constexpr (VAR != 3) {
      __builtin_amdgcn_s_setprio(1);
#pragma unroll
      for (int s = 0; s < 2; ++s)
#pragma unroll
        for (int nb = 0; nb < 4; ++nb) {
          int kk = nb * 16 + l15;
          int ch = (s * 4 + l4) ^ (kk & 7);
          bf16x8 kf = *(const bf16x8*)&Kl[cur][kk * 64 + ch * 8];
          sA[nb] = __builtin_amdgcn_mfma_f32_16x16x32_bf16(kf, qfA[s], sA[nb], 0, 0, 0);
          sB[nb] = __builtin_amdgcn_mfma_f32_16x16x32_bf16(kf, qfB[s], sB[nb], 0, 0, 0);
        }
      __builtin_amdgcn_s_setprio(0);
    } else {
      // synthetic kt-varying scores (keeps SM+PV work realistic, no QK/kf)
      float base = (float)kt * 0.015625f + (float)l15 * 0.001f;
#pragma unroll
      for (int nb = 0; nb < 4; ++nb)
#pragma unroll
        for (int r = 0; r < 4; ++r) {
          sA[nb][r] = base + (float)(nb * 4 + r) * 0.01f;
          sB[nb][r] = base + (float)(nb * 4 + r) * 0.02f;
        }
    }

    bf16x8 pfA[2], pfB[2];
    if constexpr (VAR == 1) {
      // noSM: pack raw scores (QK stays live), skip mask/max/exp/sum
#pragma unroll
      for (int s = 0; s < 2; ++s) {
        u32x4 wa, wb;
        wa.x = cvt_pk_bf16(sA[2 * s][0], sA[2 * s][1]);
        wb.x = cvt_pk_bf16(sB[2 * s][0], sB[2 * s][1]);
        wa.y = cvt_pk_bf16(sA[2 * s][2], sA[2 * s][3]);
        wb.y = cvt_pk_bf16(sB[2 * s][2], sB[2 * s][3]);
        wa.z = cvt_pk_bf16(sA[2 * s + 1][0], sA[2 * s + 1][1]);
        wb.z = cvt_pk_bf16(sB[2 * s + 1][0], sB[2 * s + 1][1]);
        wa.w = cvt_pk_bf16(sA[2 * s + 1][2], sA[2 * s + 1][3]);
        wb.w = cvt_pk_bf16(sB[2 * s + 1][2], sB[2 * s + 1][3]);
        pfA[s] = __builtin_bit_cast(bf16x8, wa);
        pfB[s] = __builtin_bit_cast(bf16x8, wb);
      }
      lsA += 1.0f;
      lsB += 1.0f;
    } else {
      float vA[16], vB[16];
#pragma unroll
      for (int nb = 0; nb < 4; ++nb)
#pragma unroll
        for (int r = 0; r < 4; ++r) {
          vA[nb * 4 + r] = sA[nb][r];
          vB[nb * 4 + r] = sB[nb][r];
        }
      if (kt == qtB) {
        int qg = wave * 16 + l15;
#pragma unroll
        for (int i = 0; i < 16; ++i) {
          int kg = (i >> 2) * 16 + l4 * 4 + (i & 3);
          if (kg > qg) vB[i] = -1e30f;
        }
      }
      float tA[8], tB[8];
#pragma unroll
      for (int i = 0; i < 8; ++i) {
        tA[i] = fmaxf(vA[2 * i], vA[2 * i + 1]);
        tB[i] = fmaxf(vB[2 * i], vB[2 * i + 1]);
      }
#pragma unroll
      for (int i = 0; i < 4; ++i) {
        tA[i] = fmaxf(tA[i], tA[i + 4]);
        tB[i] = fmaxf(tB[i], tB[i + 4]);
      }
      float mxA = fmaxf(fmaxf(tA[0], tA[2]), fmaxf(tA[1], tA[3]));
      float mxB = fmaxf(fmaxf(tB[0], tB[2]), fmaxf(tB[1], tB[3]));
      if (!__all(fmaxf(mxA - mA, mxB - mB) <= 8.0f)) {
        float mrA = fmaxf(mxA, __shfl_xor(mxA, 16));
        float mrB = fmaxf(mxB, __shfl_xor(mxB, 16));
        mrA = fmaxf(mrA, __shfl_xor(mrA, 32));
        mrB = fmaxf(mrB, __shfl_xor(mrB, 32));
        float mnA = fmaxf(mA, mrA), mnB = fmaxf(mB, mrB);
        float aA = ex2(mA - mnA), aB = ex2(mB - mnB);
        mA = mnA;
        mB = mnB;
        lsA *= aA;
        lsB *= aB;
#pragma unroll
        for (int hb = 0; hb < 4; ++hb)
#pragma unroll
          for (int r = 0; r < 4; ++r) {
            oA[hb][r] *= aA;
            oB[hb][r] *= aB;
          }
      }
      float pA[16], pB[16];
#pragma unroll
      for (int i = 0; i < 16; ++i) {
        pA[i] = ex2(vA[i] - mA);
        pB[i] = ex2(vB[i] - mB);
      }
      float uA[8], uB[8];
#pragma unroll
      for (int i = 0; i < 8; ++i) {
        uA[i] = pA[2 * i] + pA[2 * i + 1];
        uB[i] = pB[2 * i] + pB[2 * i + 1];
      }
#pragma unroll
      for (int i = 0; i < 4; ++i) {
        uA[i] += uA[i + 4];
        uB[i] += uB[i + 4];
      }
      lsA += (uA[0] + uA[2]) + (uA[1] + uA[3]);
      lsB += (uB[0] + uB[2]) + (uB[1] + uB[3]);
#pragma unroll
      for (int s = 0; s < 2; ++s) {
        u32x4 wa, wb;
        wa.x = cvt_pk_bf16(pA[8 * s + 0], pA[8 * s + 1]);
        wb.x = cvt_pk_bf16(pB[8 * s + 0], pB[8 * s + 1]);
        wa.y = cvt_pk_bf16(pA[8 * s + 2], pA[8 * s + 3]);
        wb.y = cvt_pk_bf16(pB[8 * s + 2], pB[8 * s + 3]);
        wa.z = cvt_pk_bf16(pA[8 * s + 4], pA[8 * s + 5]);
        wb.z = cvt_pk_bf16(pB[8 * s + 4], pB[8 * s + 5]);
        wa.w = cvt_pk_bf16(pA[8 * s + 6], pA[8 * s + 7]);
        wb.w = cvt_pk_bf16(pB[8 * s + 6], pB[8 * s + 7]);
        pfA[s] = __builtin_bit_cast(bf16x8, wa);
        pfB[s] = __builtin_bit_cast(bf16x8, wb);
      }
    }

    if constexpr (VAR == 2) {
      // noPV: keep pf live, skip tr-reads and PV MFMAs
      asm volatile("" ::"v"(pfA[0]), "v"(pfA[1]), "v"(pfB[0]), "v"(pfB[1]));
    } else {
      bf16x8 vf[2][4];
#pragma unroll
      for (int s = 0; s < 2; ++s)
#pragma unroll
        for (int hb = 0; hb < 4; ++hb) {
          bf16x4 ta = tr16(&Vtr[cur][(hb * 16 + s * 8) * 64 + lane * 4]);
          bf16x4 tb = tr16(&Vtr[cur][(hb * 16 + s * 8 + 4) * 64 + lane * 4]);
          vf[s][hb] = __builtin_shufflevector(ta, tb, 0, 1, 2, 3, 4, 5, 6, 7);
        }
      asm volatile("s_waitcnt lgkmcnt(0)" ::: "memory");
      __builtin_amdgcn_sched_barrier(0);
      __builtin_amdgcn_s_setprio(1);
#pragma unroll
      for (int s = 0; s < 2; ++s)
#pragma unroll
        for (int hb = 0; hb < 4; ++hb) {
          oA[hb] = __builtin_amdgcn_mfma_f32_16x16x32_bf16(vf[s][hb], pfA[s], oA[hb], 0, 0, 0);
          oB[hb] = __builtin_amdgcn_mfma_f32_16x16x32_bf16(vf[s][hb], pfB[s], oB[hb], 0, 0, 0);
        }
      __builtin_amdgcn_s_setprio(0);
    }

    __builtin_amdgcn_s_barrier();
    __builtin_amdgcn_sched_barrier(0);
    int nt = kt + 3 > qtA ? qtA : kt + 3;
    stage(cur, nt);
    cur = cur == 2 ? 0 : cur + 1;
  }

  // ======== phase 2: A only ========
#pragma unroll 1
  for (; kt <= qtA; ++kt) {
    asm volatile("s_waitcnt vmcnt(8)" ::: "memory");
    __builtin_amdgcn_s_barrier();
    __builtin_amdgcn_sched_barrier(0);

    f32x4 sA[4] = {fz, fz, fz, fz};
    if constexpr (VAR != 3) {
      __builtin_amdgcn_s_setprio(1);
#pragma unroll
      for (int s = 0; s < 2; ++s)
#pragma unroll
        for (int nb = 0; nb < 4; ++nb) {
          int kk = nb * 16 + l15;
          int ch = (s * 4 + l4) ^ (kk & 7);
          bf16x8 kf = *(const bf16x8*)&Kl[cur][kk * 64 + ch * 8];
          sA[nb] = __builtin_amdgcn_mfma_f32_16x16x32_bf16(kf, qfA[s], sA[nb], 0, 0, 0);
        }
      __builtin_amdgcn_s_setprio(0);
    } else {
      float base = (float)kt * 0.015625f + (float)l15 * 0.001f;
#pragma unroll
      for (int nb = 0; nb < 4; ++nb)
#pragma unroll
        for (int r = 0; r < 4; ++r) sA[nb][r] = base + (float)(nb * 4 + r) * 0.01f;
    }

    bf16x8 pfA[2];
    if constexpr (VAR == 1) {
#pragma unroll
      for (int s = 0; s < 2; ++s) {
        u32x4 wa;
        wa.x = cvt_pk_bf16(sA[2 * s][0], sA[2 * s][1]);
        wa.y = cvt_pk_bf16(sA[2 * s][2], sA[2 * s][3]);
        wa.z = cvt_pk_bf16(sA[2 * s + 1][0], sA[2 * s + 1][1]);
        wa.w = cvt_pk_bf16(sA[2 * s + 1][2], sA[2 * s + 1][3]);
        pfA[s] = __builtin_bit_cast(bf16x8, wa);
      }
      lsA += 1.0f;
    } else {
      float vA[16];
#pragma unroll
      for (int nb = 0; nb < 4; ++nb)
#pragma unroll
        for (int r = 0; r < 4; ++r) vA[nb * 4 + r] = sA[nb][r];
      if (kt == qtA) {
        int qg = wave * 16 + l15;
#pragma unroll
        for (int i = 0; i < 16; ++i) {
          int kg = (i >> 2) * 16 + l4 * 4 + (i & 3);
          if (kg > qg) vA[i] = -1e30f;
        }
      }
      float tA[8];
#pragma unroll
      for (int i = 0; i < 8; ++i) tA[i] = fmaxf(vA[2 * i], vA[2 * i + 1]);
#pragma unroll
      for (int i = 0; i < 4; ++i) tA[i] = fmaxf(tA[i], tA[i + 4]);
      float mxA = fmaxf(fmaxf(tA[0], tA[2]), fmaxf(tA[1], tA[3]));
      if (!__all(mxA <= mA + 8.0f)) {
        float mrA = fmaxf(mxA, __shfl_xor(mxA, 16));
        mrA = fmaxf(mrA, __shfl_xor(mrA, 32));
        float mnA = fmaxf(mA, mrA);
        float aA = ex2(mA - mnA);
        mA = mnA;
        lsA *= aA;
#pragma unroll
        for (int hb = 0; hb < 4; ++hb)
#pragma unroll
          for (int r = 0; r < 4; ++r) oA[hb][r] *= aA;
      }
      float pA[16];
#pragma unroll
      for (int i = 0; i < 16; ++i) pA[i] = ex2(vA[i] - mA);
      float uA[8];
#pragma unroll
      for (int i = 0; i < 8; ++i) uA[i] = pA[2 * i] + pA[2 * i + 1];
#pragma unroll
      for (int i = 0; i < 4; ++i) uA[i] += uA[i + 4];
      lsA += (uA[0] + uA[2]) + (uA[1] + uA[3]);
#pragma unroll
      for (int s = 0; s < 2; ++s) {
        u32x4 wa;
        wa.x = cvt_pk_bf16(pA[8 * s + 0], pA[8 * s + 1]);
        wa.y = cvt_pk_bf16(pA[8 * s + 2], pA[8 * s + 3]);
        wa.z = cvt_pk_bf16(pA[8 * s + 4], pA[8 * s + 5]);
        wa.w = cvt_pk_bf16(pA[8 * s + 6], pA[8 * s + 7]);
        pfA[s] = __builtin_bit_cast(bf16x8, wa);
      }
    }

    if constexpr (VAR == 2) {
      asm volatile("" ::"v"(pfA[0]), "v"(pfA[1]));
    } else {
      bf16x8 vf[2][4];
#pragma unroll
      for (int s = 0; s < 2; ++s)
#pragma unroll
        for (int hb = 0; hb < 4; ++hb) {
          bf16x4 ta = tr16(&Vtr[cur][(hb * 16 + s * 8) * 64 + lane * 4]);
          bf16x4 tb = tr16(&Vtr[cur][(hb * 16 + s * 8 + 4) * 64 + lane * 4]);
          vf[s][hb] = __builtin_shufflevector(ta, tb, 0, 1, 2, 3, 4, 5, 6, 7);
        }
      asm volatile("s_waitcnt lgkmcnt(0)" ::: "memory");
      __builtin_amdgcn_sched_barrier(0);
      __builtin_amdgcn_s_setprio(1);
#pragma unroll
      for (int s = 0; s < 2; ++s)
#pragma unroll
        for (int hb = 0; hb < 4; ++hb)
          oA[hb] = __builtin_amdgcn_mfma_f32_16x16x32_bf16(vf[s][hb], pfA[s], oA[hb], 0, 0, 0);
      __builtin_amdgcn_s_setprio(0);
    }

    __builtin_amdgcn_s_barrier();
    __builtin_amdgcn_sched_barrier(0);
    int nt = kt + 3 > qtA ? qtA : kt + 3;
    stage(cur, nt);
    cur = cur == 2 ? 0 : cur + 1;
  }

  // epilogue
  auto epi = [&](f32x4* accO, float lsum, int qt) {
    float t = lsum + __shfl_xor(lsum, 16);
    t += __shfl_xor(t, 32);
    float inv = 1.0f / t;
    int qg = qt * 64 + wave * 16 + l15;
    u16* yrow = Y + (size_t)(b * 2048 + qg) * 1024 + h * 64;
#pragma unroll
    for (int hb = 0; hb < 4; ++hb) {
      uint2 pk;
      pk.x = cvt_pk_bf16(accO[hb][0] * inv, accO[hb][1] * inv);
      pk.y = cvt_pk_bf16(accO[hb][2] * inv, accO[hb][3] * inv);
      *(uint2*)&yrow[hb * 16 + l4 * 4] = pk;
    }
  };
  epi(oA, lsA, qtA);
  epi(oB, lsB, qtB);
}

extern "C" void kernel_launch(void* const* d_in, const int* in_sizes, int n_in,
                              void* d_out, int out_size, void* d_ws, size_t ws_size,
                              hipStream_t stream) {
  const float* x = (const float*)d_in[0];       // [2,2048,1024]
  const float* Wqkv = (const float*)d_in[1];    // [1024,3072]
  const float* Wproj = (const float*)d_in[2];   // [1024,1024]
  float* out = (float*)d_out;                   // [2,2048,1024] f32

  char* ws = (char*)d_ws;
  u16* Xb  = (u16*)(ws + 0);                    // 8 MB  [4096][1024]
  u16* Wqt = (u16*)(ws + ((size_t)8 << 20));    // 6 MB  [3072][1024]
  u16* Wpt = (u16*)(ws + ((size_t)14 << 20));   // 2 MB  [1024][1024]
  u16* Qs  = (u16*)(ws + ((size_t)16 << 20));   // 8 MB  [2,16,2048,64]
  u16* Ks  = (u16*)(ws + ((size_t)24 << 20));   // 8 MB
  u16* Vs  = (u16*)(ws + ((size_t)32 << 20));   // 8 MB
  u16* Yb  = (u16*)(ws + ((size_t)40 << 20));   // 8 MB  [4096][1024]
  // ablation scratch: d_out is dead until k_gemm<1> fully overwrites it
  u16* Scr = (u16*)d_out;

  k_cast<<<2048, 256, 0, stream>>>(x, Xb, 4096 * 1024 / 8);
  k_tcast<<<dim3(96, 32), 256, 0, stream>>>(Wqkv, Wqt, 1024, 3072);
  k_tcast<<<dim3(32, 32), 256, 0, stream>>>(Wproj, Wpt, 1024, 1024);
  k_gemm<0><<<dim3(24, 32), 256, 0, stream>>>(Xb, Wqt, Qs, Ks, Vs, nullptr, 1024);
  k_attn<0><<<dim3(16, 32), 256, 0, stream>>>(Qs, Ks, Vs, Yb);   // real
  k_attn<1><<<dim3(16, 32), 256, 0, stream>>>(Qs, Ks, Vs, Scr);  // noSM
  k_attn<2><<<dim3(16, 32), 256, 0, stream>>>(Qs, Ks, Vs, Scr);  // noPV
  k_attn<3><<<dim3(16, 32), 256, 0, stream>>>(Qs, Ks, Vs, Scr);  // noQK
  k_gemm<1><<<dim3(8, 32), 256, 0, stream>>>(Yb, Wpt, nullptr, nullptr, nullptr, out, 1024);
}

// Round 11
// 139.884 us; speedup vs baseline: 1.5745x; 1.5745x over previous
//
#include <hip/hip_runtime.h>

typedef __bf16 bf16x8 __attribute__((ext_vector_type(8)));
typedef __bf16 bf16x4 __attribute__((ext_vector_type(4)));
typedef float f32x4 __attribute__((ext_vector_type(4)));
typedef unsigned short u16;
typedef unsigned int u32;
typedef u32 u32x4 __attribute__((ext_vector_type(4)));

// round-to-nearest-even f32 -> bf16
__device__ __forceinline__ u16 f2bf(float f) {
  u32 u = __builtin_bit_cast(u32, f);
  u += 0x7fffu + ((u >> 16) & 1u);
  return (u16)(u >> 16);
}

// packed f32x2 -> bf16x2 (RNE); low u16 = first arg (verified R2/R4)
__device__ __forceinline__ u32 cvt_pk_bf16(float lo, float hi) {
  u32 r;
  asm("v_cvt_pk_bf16_f32 %0, %1, %2" : "=v"(r) : "v"(lo), "v"(hi));
  return r;
}

// raw v_exp_f32: r = 2^x (scores pre-scaled to log2 domain)
__device__ __forceinline__ float ex2(float x) {
  float r;
  asm("v_exp_f32 %0, %1" : "=v"(r) : "v"(x));
  return r;
}

// async global->LDS, 16B per lane. LDS dest = wave-uniform base (HW adds lane*16).
__device__ __forceinline__ void gl_lds16(const u16* g, u16* l) {
  __builtin_amdgcn_global_load_lds(
      (const __attribute__((address_space(1))) u32*)g,
      (__attribute__((address_space(3))) u32*)l, 16, 0, 0);
}

// LDS transpose read. Per-lane address REQUIRED: p = base + lane*4 (elems).
// Lane l receives elems base[(l>>4)*64 + j*16 + (l&15)], j=0..3 (verified R4).
__device__ __forceinline__ bf16x4 tr16(const u16* p) {
  bf16x4 r;
  auto lp = (const __attribute__((address_space(3))) u16*)p;
  asm volatile("ds_read_b64_tr_b16 %0, %1" : "=&v"(r) : "v"(lp));
  return r;
}

// ---------------- cast x: f32 -> bf16, 8 elems/thread ----------------
__global__ __launch_bounds__(256) void k_cast(const float* __restrict__ in,
                                              u16* __restrict__ out, int n8) {
  int i = blockIdx.x * 256 + threadIdx.x;
  if (i >= n8) return;
  const float4* p = (const float4*)in + (size_t)i * 2;
  float4 a = p[0], b = p[1];
  u16 r[8] = {f2bf(a.x), f2bf(a.y), f2bf(a.z), f2bf(a.w),
              f2bf(b.x), f2bf(b.y), f2bf(b.z), f2bf(b.w)};
  ((uint4*)out)[i] = *(const uint4*)r;
}

// ---------- transpose+cast: W [K][N] f32 -> Wt [N][K] bf16 ----------
__global__ __launch_bounds__(256) void k_tcast(const float* __restrict__ in,
                                               u16* __restrict__ out, int K, int N) {
  __shared__ float tile[32][33];
  int n0 = blockIdx.x * 32, k0 = blockIdx.y * 32;
  int c = threadIdx.x & 31, r0 = (threadIdx.x >> 5) * 4;
#pragma unroll
  for (int rr = 0; rr < 4; ++rr) {
    int r = r0 + rr;
    tile[r][c] = in[(size_t)(k0 + r) * N + n0 + c];
  }
  __syncthreads();
#pragma unroll
  for (int rr = 0; rr < 4; ++rr) {
    int r = r0 + rr;
    out[(size_t)(n0 + r) * K + k0 + c] = f2bf(tile[c][r]);
  }
}

// ---------------- bf16 GEMM: C[M,N] = A[M,K] * Bt[N,K]^T ----------------
template <int EPI>
__global__ __launch_bounds__(256) void k_gemm(const u16* __restrict__ A,
                                              const u16* __restrict__ Bt,
                                              u16* __restrict__ Qp, u16* __restrict__ Kp,
                                              u16* __restrict__ Vp, float* __restrict__ Cf,
                                              int K) {
  __shared__ u16 As[128 * 32];
  __shared__ u16 Bs[128 * 32];
  const int tid = threadIdx.x;
  const int lane = tid & 63, wave = tid >> 6;
  const int l15 = lane & 15, l4 = lane >> 4;
  const int wr = wave >> 1, wc = wave & 1;
  const int tm = blockIdx.y, tn = blockIdx.x;

  int srow[2], scol[2];
#pragma unroll
  for (int i = 0; i < 2; ++i) {
    int row = (wave * 2 + i) * 16 + (lane >> 2);
    srow[i] = row;
    scol[i] = ((lane & 3) ^ ((row >> 1) & 3)) * 8;
  }

  const f32x4 fz = {0.f, 0.f, 0.f, 0.f};
  f32x4 acc[4][4];
#pragma unroll
  for (int a = 0; a < 4; ++a)
#pragma unroll
    for (int b = 0; b < 4; ++b) acc[a][b] = fz;

  const int nk = K >> 5;
  for (int kt = 0; kt < nk; ++kt) {
#pragma unroll
    for (int i = 0; i < 2; ++i) {
      gl_lds16(A + (size_t)(tm * 128 + srow[i]) * K + kt * 32 + scol[i],
               &As[(wave * 2 + i) * 512]);
      gl_lds16(Bt + (size_t)(tn * 128 + srow[i]) * K + kt * 32 + scol[i],
               &Bs[(wave * 2 + i) * 512]);
    }
    __syncthreads();
    bf16x8 af[4], bfr[4];
#pragma unroll
    for (int mi = 0; mi < 4; ++mi) {
      int row = wr * 64 + mi * 16 + l15;
      int pch = l4 ^ ((row >> 1) & 3);
      af[mi] = *(const bf16x8*)&As[row * 32 + pch * 8];
    }
#pragma unroll
    for (int ni = 0; ni < 4; ++ni) {
      int row = wc * 64 + ni * 16 + l15;
      int pch = l4 ^ ((row >> 1) & 3);
      bfr[ni] = *(const bf16x8*)&Bs[row * 32 + pch * 8];
    }
#pragma unroll
    for (int mi = 0; mi < 4; ++mi)
#pragma unroll
      for (int ni = 0; ni < 4; ++ni)
        acc[mi][ni] = __builtin_amdgcn_mfma_f32_16x16x32_bf16(af[mi], bfr[ni],
                                                              acc[mi][ni], 0, 0, 0);
    __syncthreads();
  }

  const int rbase = tm * 128 + wr * 64 + l4 * 4;
  const int cbase = tn * 128 + wc * 64 + l15;
  if (EPI == 0) {
#pragma unroll
    for (int ni = 0; ni < 4; ++ni) {
      int col = cbase + ni * 16;
      int which = col >> 10;
      int d = col & 1023;
      int h = d >> 6, hd = d & 63;
      u16* dst = which == 0 ? Qp : (which == 1 ? Kp : Vp);
      float scl = which == 0 ? 0.180336880f : 1.0f;  // 0.125 * log2(e)
#pragma unroll
      for (int mi = 0; mi < 4; ++mi) {
#pragma unroll
        for (int r = 0; r < 4; ++r) {
          int rowg = rbase + mi * 16 + r;
          int b = rowg >> 11, t = rowg & 2047;
          dst[(size_t)(((b * 16 + h) * 2048 + t) * 64 + hd)] = f2bf(acc[mi][ni][r] * scl);
        }
      }
    }
  } else {
#pragma unroll
    for (int mi = 0; mi < 4; ++mi)
#pragma unroll
      for (int r = 0; r < 4; ++r) {
        int rowg = rbase + mi * 16 + r;
#pragma unroll
        for (int ni = 0; ni < 4; ++ni)
          Cf[(size_t)rowg * 1024 + cbase + ni * 16] = acc[mi][ni][r];
      }
  }
}

// ---------------- causal flash attention (v9: KVBLK=128, half the iterations) ----
// Ablation (R10) showed the per-iteration skeleton dominates (~51 of 55 µs);
// phases are nearly free. So: 128-wide k-tiles -> 17 iterations/block (was 33),
// same balanced pair decomposition (nkA+nkB = 17 for every pair).
// Double-buffered (64 KB LDS, 2 blocks/CU), 8 DMA ops/wave/stage, vmcnt(8),
// 2 raw barriers per iteration. Shared kf reads + shared tr16 between A and B.
__global__ __launch_bounds__(256) void k_attn(const u16* __restrict__ Q,
                                              const u16* __restrict__ K,
                                              const u16* __restrict__ V,
                                              u16* __restrict__ Y) {
  __shared__ u16 Kl[2][128 * 64];   // [kk][hd], chunk ^= kk&7
  __shared__ u16 Vtr[2][128 * 64];  // subtiled: ((hd>>4)*32+(k>>2))*64+(k&3)*16+(hd&15)
  const int tid = threadIdx.x, lane = tid & 63, wave = tid >> 6;
  const int l15 = lane & 15, l4 = lane >> 4;
  const int bh = blockIdx.y;
  const int pp = (blockIdx.x + ((blockIdx.y >> 4) << 3)) & 15;
  const int qtA = 31 - pp, qtB = pp;  // qtB < qtA always
  const int nkA = (qtA >> 1) + 1, nkB = (qtB >> 1) + 1;  // nkB <= nkA-1
  const u16* Qb = Q + (size_t)bh * 2048 * 64;
  const u16* Kb = K + (size_t)bh * 2048 * 64;
  const u16* Vb = V + (size_t)bh * 2048 * 64;
  const int b = bh >> 4, h = bh & 15;
  const f32x4 fz = {0.f, 0.f, 0.f, 0.f};

  // staging constants: 4 K-ops + 4 V-ops per wave, 1 KB each
  int kks[4], kcol[4], vks[4], vhds[4];
#pragma unroll
  for (int i = 0; i < 4; ++i) {
    int kk = wave * 32 + i * 8 + (lane >> 3);
    kks[i] = kk;
    kcol[i] = ((lane & 7) ^ (kk & 7)) * 8;
    int o = (wave * 4 + i) * 512 + lane * 8;
    vks[i] = ((o >> 6) & 31) * 4 + ((o >> 4) & 3);
    vhds[i] = ((o >> 11) << 4) + (o & 8);
  }

  auto stage = [&](int buf, int kt) {
#pragma unroll
    for (int i = 0; i < 4; ++i)
      gl_lds16(Kb + (size_t)(kt * 128 + kks[i]) * 64 + kcol[i],
               &Kl[buf][(wave * 4 + i) * 512]);
#pragma unroll
    for (int i = 0; i < 4; ++i)
      gl_lds16(Vb + (size_t)(kt * 128 + vks[i]) * 64 + vhds[i],
               &Vtr[buf][(wave * 4 + i) * 512]);
  };

  bf16x8 qfA[2], qfB[2];
  {
    int qrA = qtA * 64 + wave * 16 + l15;
    int qrB = qtB * 64 + wave * 16 + l15;
    qfA[0] = *(const bf16x8*)&Qb[(size_t)qrA * 64 + l4 * 8];
    qfA[1] = *(const bf16x8*)&Qb[(size_t)qrA * 64 + 32 + l4 * 8];
    qfB[0] = *(const bf16x8*)&Qb[(size_t)qrB * 64 + l4 * 8];
    qfB[1] = *(const bf16x8*)&Qb[(size_t)qrB * 64 + 32 + l4 * 8];
  }
  const int qgA = qtA * 64 + wave * 16 + l15;
  const int qgB = qtB * 64 + wave * 16 + l15;
  f32x4 oA[4] = {fz, fz, fz, fz}, oB[4] = {fz, fz, fz, fz};
  float mA = -1e30f, lsA = 0.f, mB = -1e30f, lsB = 0.f;

  stage(0, 0);
  stage(1, 1);

  int cur = 0, kt = 0;

  // ======== phase 1: both tiles active (kt in [0, nkB)) ========
#pragma unroll 1
  for (; kt < nkB; ++kt) {
    asm volatile("s_waitcnt vmcnt(8)" ::: "memory");
    __builtin_amdgcn_s_barrier();
    __builtin_amdgcn_sched_barrier(0);

    f32x4 sA[8], sB[8];
#pragma unroll
    for (int nb = 0; nb < 8; ++nb) {
      sA[nb] = fz;
      sB[nb] = fz;
    }
    __builtin_amdgcn_s_setprio(1);
#pragma unroll
    for (int s = 0; s < 2; ++s)
#pragma unroll
      for (int nb = 0; nb < 8; ++nb) {
        int kk = nb * 16 + l15;
        int ch = (s * 4 + l4) ^ (kk & 7);
        bf16x8 kf = *(const bf16x8*)&Kl[cur][kk * 64 + ch * 8];
        sA[nb] = __builtin_amdgcn_mfma_f32_16x16x32_bf16(kf, qfA[s], sA[nb], 0, 0, 0);
        sB[nb] = __builtin_amdgcn_mfma_f32_16x16x32_bf16(kf, qfB[s], sB[nb], 0, 0, 0);
      }
    __builtin_amdgcn_s_setprio(0);

    // mask B on its diagonal 128-tile
    if (kt == nkB - 1) {
#pragma unroll
      for (int nb = 0; nb < 8; ++nb)
#pragma unroll
        for (int r = 0; r < 4; ++r) {
          int kg = kt * 128 + nb * 16 + l4 * 4 + r;
          if (kg > qgB) sB[nb][r] = -1e30f;
        }
    }
    // interleaved tree max (depth 5)
    float tA[16], tB[16];
#pragma unroll
    for (int i = 0; i < 16; ++i) {
      tA[i] = fmaxf(sA[(2 * i) >> 2][(2 * i) & 3], sA[(2 * i + 1) >> 2][(2 * i + 1) & 3]);
      tB[i] = fmaxf(sB[(2 * i) >> 2][(2 * i) & 3], sB[(2 * i + 1) >> 2][(2 * i + 1) & 3]);
    }
#pragma unroll
    for (int i = 0; i < 8; ++i) {
      tA[i] = fmaxf(tA[i], tA[i + 8]);
      tB[i] = fmaxf(tB[i], tB[i + 8]);
    }
#pragma unroll
    for (int i = 0; i < 4; ++i) {
      tA[i] = fmaxf(tA[i], tA[i + 4]);
      tB[i] = fmaxf(tB[i], tB[i + 4]);
    }
    float mxA = fmaxf(fmaxf(tA[0], tA[1]), fmaxf(tA[2], tA[3]));
    float mxB = fmaxf(fmaxf(tB[0], tB[1]), fmaxf(tB[2], tB[3]));
    if (!__all(fmaxf(mxA - mA, mxB - mB) <= 8.0f)) {
      float mrA = fmaxf(mxA, __shfl_xor(mxA, 16));
      float mrB = fmaxf(mxB, __shfl_xor(mxB, 16));
      mrA = fmaxf(mrA, __shfl_xor(mrA, 32));
      mrB = fmaxf(mrB, __shfl_xor(mrB, 32));
      float mnA = fmaxf(mA, mrA), mnB = fmaxf(mB, mrB);
      float aA = ex2(mA - mnA), aB = ex2(mB - mnB);
      mA = mnA;
      mB = mnB;
      lsA *= aA;
      lsB *= aB;
#pragma unroll
      for (int hb = 0; hb < 4; ++hb)
#pragma unroll
        for (int r = 0; r < 4; ++r) {
          oA[hb][r] *= aA;
          oB[hb][r] *= aB;
        }
    }
    // per-s-block exp -> pack -> partial sums (caps live registers)
    bf16x8 pfA[4], pfB[4];
    float suA0 = 0.f, suA1 = 0.f, suB0 = 0.f, suB1 = 0.f;
#pragma unroll
    for (int s = 0; s < 4; ++s) {
      float pa[8], pb[8];
#pragma unroll
      for (int j = 0; j < 8; ++j) {
        pa[j] = ex2(sA[2 * s + (j >> 2)][j & 3] - mA);
        pb[j] = ex2(sB[2 * s + (j >> 2)][j & 3] - mB);
      }
      suA0 += (pa[0] + pa[1]) + (pa[2] + pa[3]);
      suA1 += (pa[4] + pa[5]) + (pa[6] + pa[7]);
      suB0 += (pb[0] + pb[1]) + (pb[2] + pb[3]);
      suB1 += (pb[4] + pb[5]) + (pb[6] + pb[7]);
      u32x4 wa, wb;
      wa.x = cvt_pk_bf16(pa[0], pa[1]);
      wb.x = cvt_pk_bf16(pb[0], pb[1]);
      wa.y = cvt_pk_bf16(pa[2], pa[3]);
      wb.y = cvt_pk_bf16(pb[2], pb[3]);
      wa.z = cvt_pk_bf16(pa[4], pa[5]);
      wb.z = cvt_pk_bf16(pb[4], pb[5]);
      wa.w = cvt_pk_bf16(pa[6], pa[7]);
      wb.w = cvt_pk_bf16(pb[6], pb[7]);
      pfA[s] = __builtin_bit_cast(bf16x8, wa);
      pfB[s] = __builtin_bit_cast(bf16x8, wb);
    }
    lsA += suA0 + suA1;
    lsB += suB0 + suB1;

    // shared vf tr-reads; PV over 4 k-slabs
#pragma unroll
    for (int s = 0; s < 4; ++s) {
      bf16x8 vf[4];
#pragma unroll
      for (int hb = 0; hb < 4; ++hb) {
        bf16x4 ta = tr16(&Vtr[cur][(hb * 32 + s * 8) * 64 + lane * 4]);
        bf16x4 tb = tr16(&Vtr[cur][(hb * 32 + s * 8 + 4) * 64 + lane * 4]);
        vf[hb] = __builtin_shufflevector(ta, tb, 0, 1, 2, 3, 4, 5, 6, 7);
      }
      asm volatile("s_waitcnt lgkmcnt(0)" ::: "memory");
      __builtin_amdgcn_sched_barrier(0);
      __builtin_amdgcn_s_setprio(1);
#pragma unroll
      for (int hb = 0; hb < 4; ++hb) {
        oA[hb] = __builtin_amdgcn_mfma_f32_16x16x32_bf16(vf[hb], pfA[s], oA[hb], 0, 0, 0);
        oB[hb] = __builtin_amdgcn_mfma_f32_16x16x32_bf16(vf[hb], pfB[s], oB[hb], 0, 0, 0);
      }
      __builtin_amdgcn_s_setprio(0);
    }

    __builtin_amdgcn_s_barrier();
    __builtin_amdgcn_sched_barrier(0);
    int nt = kt + 2 >= nkA ? nkA - 1 : kt + 2;
    stage(cur, nt);
    cur ^= 1;
  }

  // ======== phase 2: A only (kt in [nkB, nkA)) ========
#pragma unroll 1
  for (; kt < nkA; ++kt) {
    asm volatile("s_waitcnt vmcnt(8)" ::: "memory");
    __builtin_amdgcn_s_barrier();
    __builtin_amdgcn_sched_barrier(0);

    f32x4 sA[8];
#pragma unroll
    for (int nb = 0; nb < 8; ++nb) sA[nb] = fz;
    __builtin_amdgcn_s_setprio(1);
#pragma unroll
    for (int s = 0; s < 2; ++s)
#pragma unroll
      for (int nb = 0; nb < 8; ++nb) {
        int kk = nb * 16 + l15;
        int ch = (s * 4 + l4) ^ (kk & 7);
        bf16x8 kf = *(const bf16x8*)&Kl[cur][kk * 64 + ch * 8];
        sA[nb] = __builtin_amdgcn_mfma_f32_16x16x32_bf16(kf, qfA[s], sA[nb], 0, 0, 0);
      }
    __builtin_amdgcn_s_setprio(0);

    if (kt == nkA - 1) {
#pragma unroll
      for (int nb = 0; nb < 8; ++nb)
#pragma unroll
        for (int r = 0; r < 4; ++r) {
          int kg = kt * 128 + nb * 16 + l4 * 4 + r;
          if (kg > qgA) sA[nb][r] = -1e30f;
        }
    }
    float tA[16];
#pragma unroll
    for (int i = 0; i < 16; ++i)
      tA[i] = fmaxf(sA[(2 * i) >> 2][(2 * i) & 3], sA[(2 * i + 1) >> 2][(2 * i + 1) & 3]);
#pragma unroll
    for (int i = 0; i < 8; ++i) tA[i] = fmaxf(tA[i], tA[i + 8]);
#pragma unroll
    for (int i = 0; i < 4; ++i) tA[i] = fmaxf(tA[i], tA[i + 4]);
    float mxA = fmaxf(fmaxf(tA[0], tA[1]), fmaxf(tA[2], tA[3]));
    if (!__all(mxA <= mA + 8.0f)) {
      float mrA = fmaxf(mxA, __shfl_xor(mxA, 16));
      mrA = fmaxf(mrA, __shfl_xor(mrA, 32));
      float mnA = fmaxf(mA, mrA);
      float aA = ex2(mA - mnA);
      mA = mnA;
      lsA *= aA;
#pragma unroll
      for (int hb = 0; hb < 4; ++hb)
#pragma unroll
        for (int r = 0; r < 4; ++r) oA[hb][r] *= aA;
    }
    bf16x8 pfA[4];
    float suA0 = 0.f, suA1 = 0.f;
#pragma unroll
    for (int s = 0; s < 4; ++s) {
      float pa[8];
#pragma unroll
      for (int j = 0; j < 8; ++j) pa[j] = ex2(sA[2 * s + (j >> 2)][j & 3] - mA);
      suA0 += (pa[0] + pa[1]) + (pa[2] + pa[3]);
      suA1 += (pa[4] + pa[5]) + (pa[6] + pa[7]);
      u32x4 wa;
      wa.x = cvt_pk_bf16(pa[0], pa[1]);
      wa.y = cvt_pk_bf16(pa[2], pa[3]);
      wa.z = cvt_pk_bf16(pa[4], pa[5]);
      wa.w = cvt_pk_bf16(pa[6], pa[7]);
      pfA[s] = __builtin_bit_cast(bf16x8, wa);
    }
    lsA += suA0 + suA1;

#pragma unroll
    for (int s = 0; s < 4; ++s) {
      bf16x8 vf[4];
#pragma unroll
      for (int hb = 0; hb < 4; ++hb) {
        bf16x4 ta = tr16(&Vtr[cur][(hb * 32 + s * 8) * 64 + lane * 4]);
        bf16x4 tb = tr16(&Vtr[cur][(hb * 32 + s * 8 + 4) * 64 + lane * 4]);
        vf[hb] = __builtin_shufflevector(ta, tb, 0, 1, 2, 3, 4, 5, 6, 7);
      }
      asm volatile("s_waitcnt lgkmcnt(0)" ::: "memory");
      __builtin_amdgcn_sched_barrier(0);
      __builtin_amdgcn_s_setprio(1);
#pragma unroll
      for (int hb = 0; hb < 4; ++hb)
        oA[hb] = __builtin_amdgcn_mfma_f32_16x16x32_bf16(vf[hb], pfA[s], oA[hb], 0, 0, 0);
      __builtin_amdgcn_s_setprio(0);
    }

    __builtin_amdgcn_s_barrier();
    __builtin_amdgcn_sched_barrier(0);
    int nt = kt + 2 >= nkA ? nkA - 1 : kt + 2;
    stage(cur, nt);
    cur ^= 1;
  }

  // epilogue: merge group-partial lsum (2 shuffles), divide, store
  auto epi = [&](f32x4* accO, float lsum, int qt) {
    float t = lsum + __shfl_xor(lsum, 16);
    t += __shfl_xor(t, 32);
    float inv = 1.0f / t;
    int qg = qt * 64 + wave * 16 + l15;
    u16* yrow = Y + (size_t)(b * 2048 + qg) * 1024 + h * 64;
#pragma unroll
    for (int hb = 0; hb < 4; ++hb) {
      uint2 pk;
      pk.x = cvt_pk_bf16(accO[hb][0] * inv, accO[hb][1] * inv);
      pk.y = cvt_pk_bf16(accO[hb][2] * inv, accO[hb][3] * inv);
      *(uint2*)&yrow[hb * 16 + l4 * 4] = pk;
    }
  };
  epi(oA, lsA, qtA);
  epi(oB, lsB, qtB);
}

extern "C" void kernel_launch(void* const* d_in, const int* in_sizes, int n_in,
                              void* d_out, int out_size, void* d_ws, size_t ws_size,
                              hipStream_t stream) {
  const float* x = (const float*)d_in[0];       // [2,2048,1024]
  const float* Wqkv = (const float*)d_in[1];    // [1024,3072]
  const float* Wproj = (const float*)d_in[2];   // [1024,1024]
  float* out = (float*)d_out;                   // [2,2048,1024] f32

  char* ws = (char*)d_ws;
  u16* Xb  = (u16*)(ws + 0);                    // 8 MB  [4096][1024]
  u16* Wqt = (u16*)(ws + ((size_t)8 << 20));    // 6 MB  [3072][1024]
  u16* Wpt = (u16*)(ws + ((size_t)14 << 20));   // 2 MB  [1024][1024]
  u16* Qs  = (u16*)(ws + ((size_t)16 << 20));   // 8 MB  [2,16,2048,64]
  u16* Ks  = (u16*)(ws + ((size_t)24 << 20));   // 8 MB
  u16* Vs  = (u16*)(ws + ((size_t)32 << 20));   // 8 MB
  u16* Yb  = (u16*)(ws + ((size_t)40 << 20));   // 8 MB  [4096][1024]

  k_cast<<<2048, 256, 0, stream>>>(x, Xb, 4096 * 1024 / 8);
  k_tcast<<<dim3(96, 32), 256, 0, stream>>>(Wqkv, Wqt, 1024, 3072);
  k_tcast<<<dim3(32, 32), 256, 0, stream>>>(Wproj, Wpt, 1024, 1024);
  k_gemm<0><<<dim3(24, 32), 256, 0, stream>>>(Xb, Wqt, Qs, Ks, Vs, nullptr, 1024);
  k_attn<<<dim3(16, 32), 256, 0, stream>>>(Qs, Ks, Vs, Yb);
  k_gemm<1><<<dim3(8, 32), 256, 0, stream>>>(Yb, Wpt, nullptr, nullptr, nullptr, out, 1024);
}

// Round 12
// 120.743 us; speedup vs baseline: 1.8242x; 1.1585x over previous
//
#include <hip/hip_runtime.h>

typedef __bf16 bf16x8 __attribute__((ext_vector_type(8)));
typedef __bf16 bf16x4 __attribute__((ext_vector_type(4)));
typedef float f32x4 __attribute__((ext_vector_type(4)));
typedef unsigned short u16;
typedef unsigned int u32;
typedef u32 u32x4 __attribute__((ext_vector_type(4)));

// round-to-nearest-even f32 -> bf16
__device__ __forceinline__ u16 f2bf(float f) {
  u32 u = __builtin_bit_cast(u32, f);
  u += 0x7fffu + ((u >> 16) & 1u);
  return (u16)(u >> 16);
}

// packed f32x2 -> bf16x2 (RNE); low u16 = first arg (verified R2/R4)
__device__ __forceinline__ u32 cvt_pk_bf16(float lo, float hi) {
  u32 r;
  asm("v_cvt_pk_bf16_f32 %0, %1, %2" : "=v"(r) : "v"(lo), "v"(hi));
  return r;
}

// raw v_exp_f32: r = 2^x (scores pre-scaled to log2 domain)
__device__ __forceinline__ float ex2(float x) {
  float r;
  asm("v_exp_f32 %0, %1" : "=v"(r) : "v"(x));
  return r;
}

// async global->LDS, 16B per lane. LDS dest = wave-uniform base (HW adds lane*16).
__device__ __forceinline__ void gl_lds16(const u16* g, u16* l) {
  __builtin_amdgcn_global_load_lds(
      (const __attribute__((address_space(1))) u32*)g,
      (__attribute__((address_space(3))) u32*)l, 16, 0, 0);
}

// LDS transpose read. Per-lane address REQUIRED: p = base + lane*4 (elems).
// Lane l receives elems base[(l>>4)*64 + j*16 + (l&15)], j=0..3 (verified R4).
__device__ __forceinline__ bf16x4 tr16(const u16* p) {
  bf16x4 r;
  auto lp = (const __attribute__((address_space(3))) u16*)p;
  asm volatile("ds_read_b64_tr_b16 %0, %1" : "=&v"(r) : "v"(lp));
  return r;
}

// ---------------- cast x: f32 -> bf16, 8 elems/thread ----------------
__global__ __launch_bounds__(256) void k_cast(const float* __restrict__ in,
                                              u16* __restrict__ out, int n8) {
  int i = blockIdx.x * 256 + threadIdx.x;
  if (i >= n8) return;
  const float4* p = (const float4*)in + (size_t)i * 2;
  float4 a = p[0], b = p[1];
  u16 r[8] = {f2bf(a.x), f2bf(a.y), f2bf(a.z), f2bf(a.w),
              f2bf(b.x), f2bf(b.y), f2bf(b.z), f2bf(b.w)};
  ((uint4*)out)[i] = *(const uint4*)r;
}

// ---------- transpose+cast: W [K][N] f32 -> Wt [N][K] bf16 ----------
__global__ __launch_bounds__(256) void k_tcast(const float* __restrict__ in,
                                               u16* __restrict__ out, int K, int N) {
  __shared__ float tile[32][33];
  int n0 = blockIdx.x * 32, k0 = blockIdx.y * 32;
  int c = threadIdx.x & 31, r0 = (threadIdx.x >> 5) * 4;
#pragma unroll
  for (int rr = 0; rr < 4; ++rr) {
    int r = r0 + rr;
    tile[r][c] = in[(size_t)(k0 + r) * N + n0 + c];
  }
  __syncthreads();
#pragma unroll
  for (int rr = 0; rr < 4; ++rr) {
    int r = r0 + rr;
    out[(size_t)(n0 + r) * K + k0 + c] = f2bf(tile[c][r]);
  }
}

// ---------------- bf16 GEMM: C[M,N] = A[M,K] * Bt[N,K]^T ----------------
// 128x128 tile, 4 waves (2x2), BK=32. XCD-aware block swizzle (T1).
// EPI 0: coalesced QKV epilogue via LDS re-tile (Q scaled to exp2 domain).
// EPI 1: f32 C write (row stride 1024).
template <int EPI>
__global__ __launch_bounds__(256) void k_gemm(const u16* __restrict__ A,
                                              const u16* __restrict__ Bt,
                                              u16* __restrict__ Qp, u16* __restrict__ Kp,
                                              u16* __restrict__ Vp, float* __restrict__ Cf,
                                              int K) {
  __shared__ u16 As[128 * 32];
  __shared__ u16 Bs[128 * 32];
  __shared__ u16 Cs[128 * 136];  // EPI0 epilogue staging (padded: +8 kills conflicts)
  const int tid = threadIdx.x;
  const int lane = tid & 63, wave = tid >> 6;
  const int l15 = lane & 15, l4 = lane >> 4;
  const int wr = wave >> 1, wc = wave & 1;
  // XCD-aware swizzle: consecutive wg share tm (A-panel) within one XCD's L2.
  const int lid = blockIdx.y * gridDim.x + blockIdx.x;
  const int cpx = (gridDim.x * gridDim.y) >> 3;
  const int wg = (lid & 7) * cpx + (lid >> 3);
  const int tm = wg / gridDim.x, tn = wg % gridDim.x;

  int srow[2], scol[2];
#pragma unroll
  for (int i = 0; i < 2; ++i) {
    int row = (wave * 2 + i) * 16 + (lane >> 2);
    srow[i] = row;
    scol[i] = ((lane & 3) ^ ((row >> 1) & 3)) * 8;
  }

  const f32x4 fz = {0.f, 0.f, 0.f, 0.f};
  f32x4 acc[4][4];
#pragma unroll
  for (int a = 0; a < 4; ++a)
#pragma unroll
    for (int b = 0; b < 4; ++b) acc[a][b] = fz;

  const int nk = K >> 5;
  for (int kt = 0; kt < nk; ++kt) {
#pragma unroll
    for (int i = 0; i < 2; ++i) {
      gl_lds16(A + (size_t)(tm * 128 + srow[i]) * K + kt * 32 + scol[i],
               &As[(wave * 2 + i) * 512]);
      gl_lds16(Bt + (size_t)(tn * 128 + srow[i]) * K + kt * 32 + scol[i],
               &Bs[(wave * 2 + i) * 512]);
    }
    __syncthreads();
    bf16x8 af[4], bfr[4];
#pragma unroll
    for (int mi = 0; mi < 4; ++mi) {
      int row = wr * 64 + mi * 16 + l15;
      int pch = l4 ^ ((row >> 1) & 3);
      af[mi] = *(const bf16x8*)&As[row * 32 + pch * 8];
    }
#pragma unroll
    for (int ni = 0; ni < 4; ++ni) {
      int row = wc * 64 + ni * 16 + l15;
      int pch = l4 ^ ((row >> 1) & 3);
      bfr[ni] = *(const bf16x8*)&Bs[row * 32 + pch * 8];
    }
#pragma unroll
    for (int mi = 0; mi < 4; ++mi)
#pragma unroll
      for (int ni = 0; ni < 4; ++ni)
        acc[mi][ni] = __builtin_amdgcn_mfma_f32_16x16x32_bf16(af[mi], bfr[ni],
                                                              acc[mi][ni], 0, 0, 0);
    __syncthreads();
  }

  if (EPI == 0) {
    // stage scaled bf16 C-tile in LDS, then 16B-coalesced writes into Q/K/V
#pragma unroll
    for (int ni = 0; ni < 4; ++ni) {
      int colb = wc * 64 + ni * 16;
      float scl = ((tn * 128 + colb) >> 10) == 0 ? 0.180336880f : 1.0f;  // 0.125*log2e
#pragma unroll
      for (int mi = 0; mi < 4; ++mi)
#pragma unroll
        for (int r = 0; r < 4; ++r) {
          int rowb = wr * 64 + mi * 16 + l4 * 4 + r;
          Cs[rowb * 136 + colb + l15] = f2bf(acc[mi][ni][r] * scl);
        }
    }
    __syncthreads();
#pragma unroll
    for (int pass = 0; pass < 8; ++pass) {
      int rowb = pass * 16 + (tid >> 4);
      int colb = (tid & 15) * 8;
      uint4 v = *(const uint4*)&Cs[rowb * 136 + colb];
      int rowg = tm * 128 + rowb;
      int b = rowg >> 11, t = rowg & 2047;
      int gcol = tn * 128 + colb;
      int which = gcol >> 10;
      int d = gcol & 1023;
      int h = d >> 6, hd = d & 63;
      u16* dst = which == 0 ? Qp : (which == 1 ? Kp : Vp);
      *(uint4*)&dst[(size_t)(((b * 16 + h) * 2048 + t) * 64 + hd)] = v;
    }
  } else {
    const int rbase = tm * 128 + wr * 64 + l4 * 4;
    const int cbase = tn * 128 + wc * 64 + l15;
#pragma unroll
    for (int mi = 0; mi < 4; ++mi)
#pragma unroll
      for (int r = 0; r < 4; ++r) {
        int rowg = rbase + mi * 16 + r;
#pragma unroll
        for (int ni = 0; ni < 4; ++ni)
          Cf[(size_t)rowg * 1024 + cbase + ni * 16] = acc[mi][ni][r];
      }
  }
}

// ---------------- causal flash attention (R8 structure + 4-deep prefetch) ----------
// grid (pair=16, bh=32); q-tiles qtA=31-p (always >qtB) and qtB=p.
// Phase 1 fuses A and B in one basic block; shared kf reads and vf tr-reads.
// QUAD-buffered staging, vmcnt(12): tiles kt+1..kt+3 stay in flight (depth 3.5).
__global__ __launch_bounds__(256) void k_attn(const u16* __restrict__ Q,
                                              const u16* __restrict__ K,
                                              const u16* __restrict__ V,
                                              u16* __restrict__ Y) {
  __shared__ u16 Kl[4][64 * 64];   // [kk][hd], chunk ^= kk&7
  __shared__ u16 Vtr[4][64 * 64];  // subtiled: ((hd>>4)*16+(k>>2))*64+(k&3)*16+(hd&15)
  const int tid = threadIdx.x, lane = tid & 63, wave = tid >> 6;
  const int l15 = lane & 15, l4 = lane >> 4;
  const int bh = blockIdx.y;
  const int pp = (blockIdx.x + ((blockIdx.y >> 4) << 3)) & 15;
  const int qtA = 31 - pp, qtB = pp;  // qtB < qtA always
  const u16* Qb = Q + (size_t)bh * 2048 * 64;
  const u16* Kb = K + (size_t)bh * 2048 * 64;
  const u16* Vb = V + (size_t)bh * 2048 * 64;
  const int b = bh >> 4, h = bh & 15;
  const f32x4 fz = {0.f, 0.f, 0.f, 0.f};

  const int kk0 = wave * 16 + (lane >> 3);
  const int kk1 = kk0 + 8;
  const int lcol0 = ((lane & 7) ^ (kk0 & 7)) * 8;
  const int lcol1 = ((lane & 7) ^ (kk1 & 7)) * 8;
  int vk[2], vhd[2];
#pragma unroll
  for (int i = 0; i < 2; ++i) {
    int o = (wave * 2 + i) * 512 + lane * 8;
    vk[i] = ((o >> 6) & 15) * 4 + ((o >> 4) & 3);
    vhd[i] = ((o >> 10) << 4) + (o & 8);
  }

  // 4 VMEM ops per wave per stage
  auto stage = [&](int buf, int kt) {
    gl_lds16(Kb + (size_t)(kt * 64 + kk0) * 64 + lcol0, &Kl[buf][(wave * 2 + 0) * 512]);
    gl_lds16(Kb + (size_t)(kt * 64 + kk1) * 64 + lcol1, &Kl[buf][(wave * 2 + 1) * 512]);
    gl_lds16(Vb + (size_t)(kt * 64 + vk[0]) * 64 + vhd[0], &Vtr[buf][(wave * 2 + 0) * 512]);
    gl_lds16(Vb + (size_t)(kt * 64 + vk[1]) * 64 + vhd[1], &Vtr[buf][(wave * 2 + 1) * 512]);
  };

  bf16x8 qfA[2], qfB[2];
  {
    int qrA = qtA * 64 + wave * 16 + l15;
    int qrB = qtB * 64 + wave * 16 + l15;
    qfA[0] = *(const bf16x8*)&Qb[(size_t)qrA * 64 + l4 * 8];
    qfA[1] = *(const bf16x8*)&Qb[(size_t)qrA * 64 + 32 + l4 * 8];
    qfB[0] = *(const bf16x8*)&Qb[(size_t)qrB * 64 + l4 * 8];
    qfB[1] = *(const bf16x8*)&Qb[(size_t)qrB * 64 + 32 + l4 * 8];
  }
  f32x4 oA[4] = {fz, fz, fz, fz}, oB[4] = {fz, fz, fz, fz};
  float mA = -1e30f, lsA = 0.f, mB = -1e30f, lsB = 0.f;

  // prologue: 4 tiles in flight (qtA >= 16 always)
  stage(0, 0);
  stage(1, 1);
  stage(2, 2);
  stage(3, 3);

  int cur = 0, kt = 0;

  // ======== phase 1: both tiles active (kt = 0..qtB) ========
#pragma unroll 1
  for (; kt <= qtB; ++kt) {
    asm volatile("s_waitcnt vmcnt(12)" ::: "memory");
    __builtin_amdgcn_s_barrier();
    __builtin_amdgcn_sched_barrier(0);

    f32x4 sA[4] = {fz, fz, fz, fz}, sB[4] = {fz, fz, fz, fz};
    __builtin_amdgcn_s_setprio(1);
#pragma unroll
    for (int s = 0; s < 2; ++s)
#pragma unroll
      for (int nb = 0; nb < 4; ++nb) {
        int kk = nb * 16 + l15;
        int ch = (s * 4 + l4) ^ (kk & 7);
        bf16x8 kf = *(const bf16x8*)&Kl[cur][kk * 64 + ch * 8];
        sA[nb] = __builtin_amdgcn_mfma_f32_16x16x32_bf16(kf, qfA[s], sA[nb], 0, 0, 0);
        sB[nb] = __builtin_amdgcn_mfma_f32_16x16x32_bf16(kf, qfB[s], sB[nb], 0, 0, 0);
      }
    __builtin_amdgcn_s_setprio(0);

    float vA[16], vB[16];
#pragma unroll
    for (int nb = 0; nb < 4; ++nb)
#pragma unroll
      for (int r = 0; r < 4; ++r) {
        vA[nb * 4 + r] = sA[nb][r];
        vB[nb * 4 + r] = sB[nb][r];
      }
    if (kt == qtB) {
      int qg = wave * 16 + l15;
#pragma unroll
      for (int i = 0; i < 16; ++i) {
        int kg = (i >> 2) * 16 + l4 * 4 + (i & 3);
        if (kg > qg) vB[i] = -1e30f;
      }
    }
    float tA[8], tB[8];
#pragma unroll
    for (int i = 0; i < 8; ++i) {
      tA[i] = fmaxf(vA[2 * i], vA[2 * i + 1]);
      tB[i] = fmaxf(vB[2 * i], vB[2 * i + 1]);
    }
#pragma unroll
    for (int i = 0; i < 4; ++i) {
      tA[i] = fmaxf(tA[i], tA[i + 4]);
      tB[i] = fmaxf(tB[i], tB[i + 4]);
    }
    float mxA = fmaxf(fmaxf(tA[0], tA[2]), fmaxf(tA[1], tA[3]));
    float mxB = fmaxf(fmaxf(tB[0], tB[2]), fmaxf(tB[1], tB[3]));
    if (!__all(fmaxf(mxA - mA, mxB - mB) <= 8.0f)) {
      float mrA = fmaxf(mxA, __shfl_xor(mxA, 16));
      float mrB = fmaxf(mxB, __shfl_xor(mxB, 16));
      mrA = fmaxf(mrA, __shfl_xor(mrA, 32));
      mrB = fmaxf(mrB, __shfl_xor(mrB, 32));
      float mnA = fmaxf(mA, mrA), mnB = fmaxf(mB, mrB);
      float aA = ex2(mA - mnA), aB = ex2(mB - mnB);
      mA = mnA;
      mB = mnB;
      lsA *= aA;
      lsB *= aB;
#pragma unroll
      for (int hb = 0; hb < 4; ++hb)
#pragma unroll
        for (int r = 0; r < 4; ++r) {
          oA[hb][r] *= aA;
          oB[hb][r] *= aB;
        }
    }
    float pA[16], pB[16];
#pragma unroll
    for (int i = 0; i < 16; ++i) {
      pA[i] = ex2(vA[i] - mA);
      pB[i] = ex2(vB[i] - mB);
    }
    float uA[8], uB[8];
#pragma unroll
    for (int i = 0; i < 8; ++i) {
      uA[i] = pA[2 * i] + pA[2 * i + 1];
      uB[i] = pB[2 * i] + pB[2 * i + 1];
    }
#pragma unroll
    for (int i = 0; i < 4; ++i) {
      uA[i] += uA[i + 4];
      uB[i] += uB[i + 4];
    }
    lsA += (uA[0] + uA[2]) + (uA[1] + uA[3]);
    lsB += (uB[0] + uB[2]) + (uB[1] + uB[3]);
    bf16x8 pfA[2], pfB[2];
#pragma unroll
    for (int s = 0; s < 2; ++s) {
      u32x4 wa, wb;
      wa.x = cvt_pk_bf16(pA[8 * s + 0], pA[8 * s + 1]);
      wb.x = cvt_pk_bf16(pB[8 * s + 0], pB[8 * s + 1]);
      wa.y = cvt_pk_bf16(pA[8 * s + 2], pA[8 * s + 3]);
      wb.y = cvt_pk_bf16(pB[8 * s + 2], pB[8 * s + 3]);
      wa.z = cvt_pk_bf16(pA[8 * s + 4], pA[8 * s + 5]);
      wb.z = cvt_pk_bf16(pB[8 * s + 4], pB[8 * s + 5]);
      wa.w = cvt_pk_bf16(pA[8 * s + 6], pA[8 * s + 7]);
      wb.w = cvt_pk_bf16(pB[8 * s + 6], pB[8 * s + 7]);
      pfA[s] = __builtin_bit_cast(bf16x8, wa);
      pfB[s] = __builtin_bit_cast(bf16x8, wb);
    }
    bf16x8 vf[2][4];
#pragma unroll
    for (int s = 0; s < 2; ++s)
#pragma unroll
      for (int hb = 0; hb < 4; ++hb) {
        bf16x4 ta = tr16(&Vtr[cur][(hb * 16 + s * 8) * 64 + lane * 4]);
        bf16x4 tb = tr16(&Vtr[cur][(hb * 16 + s * 8 + 4) * 64 + lane * 4]);
        vf[s][hb] = __builtin_shufflevector(ta, tb, 0, 1, 2, 3, 4, 5, 6, 7);
      }
    asm volatile("s_waitcnt lgkmcnt(0)" ::: "memory");
    __builtin_amdgcn_sched_barrier(0);
    __builtin_amdgcn_s_setprio(1);
#pragma unroll
    for (int s = 0; s < 2; ++s)
#pragma unroll
      for (int hb = 0; hb < 4; ++hb) {
        oA[hb] = __builtin_amdgcn_mfma_f32_16x16x32_bf16(vf[s][hb], pfA[s], oA[hb], 0, 0, 0);
        oB[hb] = __builtin_amdgcn_mfma_f32_16x16x32_bf16(vf[s][hb], pfB[s], oB[hb], 0, 0, 0);
      }
    __builtin_amdgcn_s_setprio(0);

    __builtin_amdgcn_s_barrier();
    __builtin_amdgcn_sched_barrier(0);
    int nt = kt + 4 > qtA ? qtA : kt + 4;
    stage(cur, nt);
    cur = (cur + 1) & 3;
  }

  // ======== phase 2: A only (kt = qtB+1..qtA) ========
#pragma unroll 1
  for (; kt <= qtA; ++kt) {
    asm volatile("s_waitcnt vmcnt(12)" ::: "memory");
    __builtin_amdgcn_s_barrier();
    __builtin_amdgcn_sched_barrier(0);

    f32x4 sA[4] = {fz, fz, fz, fz};
    __builtin_amdgcn_s_setprio(1);
#pragma unroll
    for (int s = 0; s < 2; ++s)
#pragma unroll
      for (int nb = 0; nb < 4; ++nb) {
        int kk = nb * 16 + l15;
        int ch = (s * 4 + l4) ^ (kk & 7);
        bf16x8 kf = *(const bf16x8*)&Kl[cur][kk * 64 + ch * 8];
        sA[nb] = __builtin_amdgcn_mfma_f32_16x16x32_bf16(kf, qfA[s], sA[nb], 0, 0, 0);
      }
    __builtin_amdgcn_s_setprio(0);

    float vA[16];
#pragma unroll
    for (int nb = 0; nb < 4; ++nb)
#pragma unroll
      for (int r = 0; r < 4; ++r) vA[nb * 4 + r] = sA[nb][r];
    if (kt == qtA) {
      int qg = wave * 16 + l15;
#pragma unroll
      for (int i = 0; i < 16; ++i) {
        int kg = (i >> 2) * 16 + l4 * 4 + (i & 3);
        if (kg > qg) vA[i] = -1e30f;
      }
    }
    float tA[8];
#pragma unroll
    for (int i = 0; i < 8; ++i) tA[i] = fmaxf(vA[2 * i], vA[2 * i + 1]);
#pragma unroll
    for (int i = 0; i < 4; ++i) tA[i] = fmaxf(tA[i], tA[i + 4]);
    float mxA = fmaxf(fmaxf(tA[0], tA[2]), fmaxf(tA[1], tA[3]));
    if (!__all(mxA <= mA + 8.0f)) {
      float mrA = fmaxf(mxA, __shfl_xor(mxA, 16));
      mrA = fmaxf(mrA, __shfl_xor(mrA, 32));
      float mnA = fmaxf(mA, mrA);
      float aA = ex2(mA - mnA);
      mA = mnA;
      lsA *= aA;
#pragma unroll
      for (int hb = 0; hb < 4; ++hb)
#pragma unroll
        for (int r = 0; r < 4; ++r) oA[hb][r] *= aA;
    }
    float pA[16];
#pragma unroll
    for (int i = 0; i < 16; ++i) pA[i] = ex2(vA[i] - mA);
    float uA[8];
#pragma unroll
    for (int i = 0; i < 8; ++i) uA[i] = pA[2 * i] + pA[2 * i + 1];
#pragma unroll
    for (int i = 0; i < 4; ++i) uA[i] += uA[i + 4];
    lsA += (uA[0] + uA[2]) + (uA[1] + uA[3]);
    bf16x8 pfA[2];
#pragma unroll
    for (int s = 0; s < 2; ++s) {
      u32x4 wa;
      wa.x = cvt_pk_bf16(pA[8 * s + 0], pA[8 * s + 1]);
      wa.y = cvt_pk_bf16(pA[8 * s + 2], pA[8 * s + 3]);
      wa.z = cvt_pk_bf16(pA[8 * s + 4], pA[8 * s + 5]);
      wa.w = cvt_pk_bf16(pA[8 * s + 6], pA[8 * s + 7]);
      pfA[s] = __builtin_bit_cast(bf16x8, wa);
    }
    bf16x8 vf[2][4];
#pragma unroll
    for (int s = 0; s < 2; ++s)
#pragma unroll
      for (int hb = 0; hb < 4; ++hb) {
        bf16x4 ta = tr16(&Vtr[cur][(hb * 16 + s * 8) * 64 + lane * 4]);
        bf16x4 tb = tr16(&Vtr[cur][(hb * 16 + s * 8 + 4) * 64 + lane * 4]);
        vf[s][hb] = __builtin_shufflevector(ta, tb, 0, 1, 2, 3, 4, 5, 6, 7);
      }
    asm volatile("s_waitcnt lgkmcnt(0)" ::: "memory");
    __builtin_amdgcn_sched_barrier(0);
    __builtin_amdgcn_s_setprio(1);
#pragma unroll
    for (int s = 0; s < 2; ++s)
#pragma unroll
      for (int hb = 0; hb < 4; ++hb)
        oA[hb] = __builtin_amdgcn_mfma_f32_16x16x32_bf16(vf[s][hb], pfA[s], oA[hb], 0, 0, 0);
    __builtin_amdgcn_s_setprio(0);

    __builtin_amdgcn_s_barrier();
    __builtin_amdgcn_sched_barrier(0);
    int nt = kt + 4 > qtA ? qtA : kt + 4;
    stage(cur, nt);
    cur = (cur + 1) & 3;
  }

  // epilogue: merge group-partial lsum (2 shuffles), divide, store
  auto epi = [&](f32x4* accO, float lsum, int qt) {
    float t = lsum + __shfl_xor(lsum, 16);
    t += __shfl_xor(t, 32);
    float inv = 1.0f / t;
    int qg = qt * 64 + wave * 16 + l15;
    u16* yrow = Y + (size_t)(b * 2048 + qg) * 1024 + h * 64;
#pragma unroll
    for (int hb = 0; hb < 4; ++hb) {
      uint2 pk;
      pk.x = cvt_pk_bf16(accO[hb][0] * inv, accO[hb][1] * inv);
      pk.y = cvt_pk_bf16(accO[hb][2] * inv, accO[hb][3] * inv);
      *(uint2*)&yrow[hb * 16 + l4 * 4] = pk;
    }
  };
  epi(oA, lsA, qtA);
  epi(oB, lsB, qtB);
}

extern "C" void kernel_launch(void* const* d_in, const int* in_sizes, int n_in,
                              void* d_out, int out_size, void* d_ws, size_t ws_size,
                              hipStream_t stream) {
  const float* x = (const float*)d_in[0];       // [2,2048,1024]
  const float* Wqkv = (const float*)d_in[1];    // [1024,3072]
  const float* Wproj = (const float*)d_in[2];   // [1024,1024]
  float* out = (float*)d_out;                   // [2,2048,1024] f32

  char* ws = (char*)d_ws;
  u16* Xb  = (u16*)(ws + 0);                    // 8 MB  [4096][1024]
  u16* Wqt = (u16*)(ws + ((size_t)8 << 20));    // 6 MB  [3072][1024]
  u16* Wpt = (u16*)(ws + ((size_t)14 << 20));   // 2 MB  [1024][1024]
  u16* Qs  = (u16*)(ws + ((size_t)16 << 20));   // 8 MB  [2,16,2048,64]
  u16* Ks  = (u16*)(ws + ((size_t)24 << 20));   // 8 MB
  u16* Vs  = (u16*)(ws + ((size_t)32 << 20));   // 8 MB
  u16* Yb  = (u16*)(ws + ((size_t)40 << 20));   // 8 MB  [4096][1024]

  k_cast<<<2048, 256, 0, stream>>>(x, Xb, 4096 * 1024 / 8);
  k_tcast<<<dim3(96, 32), 256, 0, stream>>>(Wqkv, Wqt, 1024, 3072);
  k_tcast<<<dim3(32, 32), 256, 0, stream>>>(Wproj, Wpt, 1024, 1024);
  k_gemm<0><<<dim3(24, 32), 256, 0, stream>>>(Xb, Wqt, Qs, Ks, Vs, nullptr, 1024);
  k_attn<<<dim3(16, 32), 256, 0, stream>>>(Qs, Ks, Vs, Yb);
  k_gemm<1><<<dim3(8, 32), 256, 0, stream>>>(Yb, Wpt, nullptr, nullptr, nullptr, out, 1024);
}

// Round 13
// 109.878 us; speedup vs baseline: 2.0045x; 1.0989x over previous
//
#include <hip/hip_runtime.h>

typedef __bf16 bf16x8 __attribute__((ext_vector_type(8)));
typedef __bf16 bf16x4 __attribute__((ext_vector_type(4)));
typedef float f32x4 __attribute__((ext_vector_type(4)));
typedef unsigned short u16;
typedef unsigned int u32;
typedef u32 u32x4 __attribute__((ext_vector_type(4)));

// round-to-nearest-even f32 -> bf16
__device__ __forceinline__ u16 f2bf(float f) {
  u32 u = __builtin_bit_cast(u32, f);
  u += 0x7fffu + ((u >> 16) & 1u);
  return (u16)(u >> 16);
}

// packed f32x2 -> bf16x2 (RNE); low u16 = first arg (verified R2/R4)
__device__ __forceinline__ u32 cvt_pk_bf16(float lo, float hi) {
  u32 r;
  asm("v_cvt_pk_bf16_f32 %0, %1, %2" : "=v"(r) : "v"(lo), "v"(hi));
  return r;
}

// raw v_exp_f32: r = 2^x (scores pre-scaled to log2 domain)
__device__ __forceinline__ float ex2(float x) {
  float r;
  asm("v_exp_f32 %0, %1" : "=v"(r) : "v"(x));
  return r;
}

// async global->LDS, 16B per lane. LDS dest = wave-uniform base (HW adds lane*16).
__device__ __forceinline__ void gl_lds16(const u16* g, u16* l) {
  __builtin_amdgcn_global_load_lds(
      (const __attribute__((address_space(1))) u32*)g,
      (__attribute__((address_space(3))) u32*)l, 16, 0, 0);
}

// LDS transpose read. Per-lane address REQUIRED: p = base + lane*4 (elems).
// Lane l receives elems base[(l>>4)*64 + j*16 + (l&15)], j=0..3 (verified R4).
__device__ __forceinline__ bf16x4 tr16(const u16* p) {
  bf16x4 r;
  auto lp = (const __attribute__((address_space(3))) u16*)p;
  asm volatile("ds_read_b64_tr_b16 %0, %1" : "=&v"(r) : "v"(lp));
  return r;
}

// ---------------- cast x: f32 -> bf16, 8 elems/thread ----------------
__global__ __launch_bounds__(256) void k_cast(const float* __restrict__ in,
                                              u16* __restrict__ out, int n8) {
  int i = blockIdx.x * 256 + threadIdx.x;
  if (i >= n8) return;
  const float4* p = (const float4*)in + (size_t)i * 2;
  float4 a = p[0], b = p[1];
  u16 r[8] = {f2bf(a.x), f2bf(a.y), f2bf(a.z), f2bf(a.w),
              f2bf(b.x), f2bf(b.y), f2bf(b.z), f2bf(b.w)};
  ((uint4*)out)[i] = *(const uint4*)r;
}

// ---------- transpose+cast: W [K][N] f32 -> Wt [N][K] bf16 ----------
__global__ __launch_bounds__(256) void k_tcast(const float* __restrict__ in,
                                               u16* __restrict__ out, int K, int N) {
  __shared__ float tile[32][33];
  int n0 = blockIdx.x * 32, k0 = blockIdx.y * 32;
  int c = threadIdx.x & 31, r0 = (threadIdx.x >> 5) * 4;
#pragma unroll
  for (int rr = 0; rr < 4; ++rr) {
    int r = r0 + rr;
    tile[r][c] = in[(size_t)(k0 + r) * N + n0 + c];
  }
  __syncthreads();
#pragma unroll
  for (int rr = 0; rr < 4; ++rr) {
    int r = r0 + rr;
    out[(size_t)(n0 + r) * K + k0 + c] = f2bf(tile[c][r]);
  }
}

// ---------------- bf16 GEMM: C[M,N] = A[M,K] * Bt[N,K]^T ----------------
// 128x128 tile, 4 waves (2x2), BK=64 (16 k-steps at K=1024).
// LDS union: As+Bs (32 KB, loop) share space with Cs (34.8 KB, epilogue)
// -> 4 blocks/CU. Mod-8 XOR chunk-swizzle (store-side pre-swizzled global src,
// read-side same XOR; cancellation argument as verified mod-4 version).
// EPI 0: coalesced QKV epilogue via Cs re-tile (Q scaled to exp2 domain).
// EPI 1: f32 C write.
template <int EPI>
__global__ __launch_bounds__(256) void k_gemm(const u16* __restrict__ A,
                                              const u16* __restrict__ Bt,
                                              u16* __restrict__ Qp, u16* __restrict__ Kp,
                                              u16* __restrict__ Vp, float* __restrict__ Cf,
                                              int K) {
  __shared__ char smem[128 * 136 * 2];  // 34.8 KB
  u16* As = (u16*)smem;                 // [128][64] 16 KB (loop)
  u16* Bs = (u16*)(smem + 32768 / 2 * 2);  // = smem+32768? no: 16 KB offset
  Bs = (u16*)(smem + 16384);
  u16* Cs = (u16*)smem;                 // [128][136] (epilogue only)
  const int tid = threadIdx.x;
  const int lane = tid & 63, wave = tid >> 6;
  const int l15 = lane & 15, l4 = lane >> 4;
  const int wr = wave >> 1, wc = wave & 1;
  const int tm = blockIdx.y, tn = blockIdx.x;

  // staging: 4 ops/wave per matrix; row-group g = wave*4+i covers rows g*8..g*8+7
  int srow[4], scol[4];
#pragma unroll
  for (int i = 0; i < 4; ++i) {
    srow[i] = wave * 32 + i * 8 + (lane >> 3);
    scol[i] = ((lane & 7) ^ (srow[i] & 7)) * 8;  // pre-swizzled logical col
  }

  const f32x4 fz = {0.f, 0.f, 0.f, 0.f};
  f32x4 acc[4][4];
#pragma unroll
  for (int a = 0; a < 4; ++a)
#pragma unroll
    for (int b = 0; b < 4; ++b) acc[a][b] = fz;

  const int nk = K >> 6;
  for (int kt = 0; kt < nk; ++kt) {
#pragma unroll
    for (int i = 0; i < 4; ++i)
      gl_lds16(A + (size_t)(tm * 128 + srow[i]) * K + kt * 64 + scol[i],
               &As[(wave * 4 + i) * 512]);
#pragma unroll
    for (int i = 0; i < 4; ++i)
      gl_lds16(Bt + (size_t)(tn * 128 + srow[i]) * K + kt * 64 + scol[i],
               &Bs[(wave * 4 + i) * 512]);
    __syncthreads();
    bf16x8 af[2][4], bfr[2][4];
#pragma unroll
    for (int s = 0; s < 2; ++s) {
#pragma unroll
      for (int mi = 0; mi < 4; ++mi) {
        int row = wr * 64 + mi * 16 + l15;
        int pch = (s * 4 + l4) ^ (row & 7);
        af[s][mi] = *(const bf16x8*)&As[row * 64 + pch * 8];
      }
#pragma unroll
      for (int ni = 0; ni < 4; ++ni) {
        int row = wc * 64 + ni * 16 + l15;
        int pch = (s * 4 + l4) ^ (row & 7);
        bfr[s][ni] = *(const bf16x8*)&Bs[row * 64 + pch * 8];
      }
    }
    __builtin_amdgcn_s_setprio(1);
#pragma unroll
    for (int s = 0; s < 2; ++s)
#pragma unroll
      for (int mi = 0; mi < 4; ++mi)
#pragma unroll
        for (int ni = 0; ni < 4; ++ni)
          acc[mi][ni] = __builtin_amdgcn_mfma_f32_16x16x32_bf16(af[s][mi], bfr[s][ni],
                                                                acc[mi][ni], 0, 0, 0);
    __builtin_amdgcn_s_setprio(0);
    __syncthreads();
  }

  if (EPI == 0) {
    // stage scaled bf16 C-tile in Cs (reuses As/Bs space; loop's trailing
    // syncthreads guarantees all frag reads are done), then coalesced writes.
#pragma unroll
    for (int ni = 0; ni < 4; ++ni) {
      int colb = wc * 64 + ni * 16;
      float scl = ((tn * 128 + colb) >> 10) == 0 ? 0.180336880f : 1.0f;  // 0.125*log2e
#pragma unroll
      for (int mi = 0; mi < 4; ++mi)
#pragma unroll
        for (int r = 0; r < 4; ++r) {
          int rowb = wr * 64 + mi * 16 + l4 * 4 + r;
          Cs[rowb * 136 + colb + l15] = f2bf(acc[mi][ni][r] * scl);
        }
    }
    __syncthreads();
#pragma unroll
    for (int pass = 0; pass < 8; ++pass) {
      int rowb = pass * 16 + (tid >> 4);
      int colb = (tid & 15) * 8;
      uint4 v = *(const uint4*)&Cs[rowb * 136 + colb];
      int rowg = tm * 128 + rowb;
      int b = rowg >> 11, t = rowg & 2047;
      int gcol = tn * 128 + colb;
      int which = gcol >> 10;
      int d = gcol & 1023;
      int h = d >> 6, hd = d & 63;
      u16* dst = which == 0 ? Qp : (which == 1 ? Kp : Vp);
      *(uint4*)&dst[(size_t)(((b * 16 + h) * 2048 + t) * 64 + hd)] = v;
    }
  } else {
    const int rbase = tm * 128 + wr * 64 + l4 * 4;
    const int cbase = tn * 128 + wc * 64 + l15;
#pragma unroll
    for (int mi = 0; mi < 4; ++mi)
#pragma unroll
      for (int r = 0; r < 4; ++r) {
        int rowg = rbase + mi * 16 + r;
#pragma unroll
        for (int ni = 0; ni < 4; ++ni)
          Cf[(size_t)rowg * 1024 + cbase + ni * 16] = acc[mi][ni][r];
      }
  }
}

// ---------------- causal flash attention (v10: ONE barrier per slot) ----------
// grid (pair=16, bh=32); q-tiles qtA=31-p, qtB=p fused in phase 1.
// 4 buffers; stage at iteration kt targets the buffer consumed at kt-1
// (readers provably passed this iteration's top barrier) loading tile kt+3.
// Invariant: 12 DMA ops outstanding at each top; vmcnt(8) retires tile kt.
// -> single s_barrier per slot (was 2).
__global__ __launch_bounds__(256) void k_attn(const u16* __restrict__ Q,
                                              const u16* __restrict__ K,
                                              const u16* __restrict__ V,
                                              u16* __restrict__ Y) {
  __shared__ u16 Kl[4][64 * 64];   // [kk][hd], chunk ^= kk&7
  __shared__ u16 Vtr[4][64 * 64];  // subtiled: ((hd>>4)*16+(k>>2))*64+(k&3)*16+(hd&15)
  const int tid = threadIdx.x, lane = tid & 63, wave = tid >> 6;
  const int l15 = lane & 15, l4 = lane >> 4;
  const int bh = blockIdx.y;
  const int pp = (blockIdx.x + ((blockIdx.y >> 4) << 3)) & 15;
  const int qtA = 31 - pp, qtB = pp;  // qtB < qtA always
  const u16* Qb = Q + (size_t)bh * 2048 * 64;
  const u16* Kb = K + (size_t)bh * 2048 * 64;
  const u16* Vb = V + (size_t)bh * 2048 * 64;
  const int b = bh >> 4, h = bh & 15;
  const f32x4 fz = {0.f, 0.f, 0.f, 0.f};

  const int kk0 = wave * 16 + (lane >> 3);
  const int kk1 = kk0 + 8;
  const int lcol0 = ((lane & 7) ^ (kk0 & 7)) * 8;
  const int lcol1 = ((lane & 7) ^ (kk1 & 7)) * 8;
  int vk[2], vhd[2];
#pragma unroll
  for (int i = 0; i < 2; ++i) {
    int o = (wave * 2 + i) * 512 + lane * 8;
    vk[i] = ((o >> 6) & 15) * 4 + ((o >> 4) & 3);
    vhd[i] = ((o >> 10) << 4) + (o & 8);
  }

  // 4 VMEM ops per wave per stage
  auto stage = [&](int buf, int kt) {
    gl_lds16(Kb + (size_t)(kt * 64 + kk0) * 64 + lcol0, &Kl[buf][(wave * 2 + 0) * 512]);
    gl_lds16(Kb + (size_t)(kt * 64 + kk1) * 64 + lcol1, &Kl[buf][(wave * 2 + 1) * 512]);
    gl_lds16(Vb + (size_t)(kt * 64 + vk[0]) * 64 + vhd[0], &Vtr[buf][(wave * 2 + 0) * 512]);
    gl_lds16(Vb + (size_t)(kt * 64 + vk[1]) * 64 + vhd[1], &Vtr[buf][(wave * 2 + 1) * 512]);
  };

  bf16x8 qfA[2], qfB[2];
  {
    int qrA = qtA * 64 + wave * 16 + l15;
    int qrB = qtB * 64 + wave * 16 + l15;
    qfA[0] = *(const bf16x8*)&Qb[(size_t)qrA * 64 + l4 * 8];
    qfA[1] = *(const bf16x8*)&Qb[(size_t)qrA * 64 + 32 + l4 * 8];
    qfB[0] = *(const bf16x8*)&Qb[(size_t)qrB * 64 + l4 * 8];
    qfB[1] = *(const bf16x8*)&Qb[(size_t)qrB * 64 + 32 + l4 * 8];
  }
  f32x4 oA[4] = {fz, fz, fz, fz}, oB[4] = {fz, fz, fz, fz};
  float mA = -1e30f, lsA = 0.f, mB = -1e30f, lsB = 0.f;

  // prologue: tiles 0..2 into bufs 0..2 (12 ops outstanding)
  stage(0, 0);
  stage(1, 1);
  stage(2, 2);

  int cur = 0, kt = 0;

  // ======== phase 1: both tiles active (kt = 0..qtB) ========
#pragma unroll 1
  for (; kt <= qtB; ++kt) {
    asm volatile("s_waitcnt vmcnt(8)" ::: "memory");
    __builtin_amdgcn_s_barrier();
    __builtin_amdgcn_sched_barrier(0);

    f32x4 sA[4] = {fz, fz, fz, fz}, sB[4] = {fz, fz, fz, fz};
    __builtin_amdgcn_s_setprio(1);
#pragma unroll
    for (int s = 0; s < 2; ++s)
#pragma unroll
      for (int nb = 0; nb < 4; ++nb) {
        int kk = nb * 16 + l15;
        int ch = (s * 4 + l4) ^ (kk & 7);
        bf16x8 kf = *(const bf16x8*)&Kl[cur][kk * 64 + ch * 8];
        sA[nb] = __builtin_amdgcn_mfma_f32_16x16x32_bf16(kf, qfA[s], sA[nb], 0, 0, 0);
        sB[nb] = __builtin_amdgcn_mfma_f32_16x16x32_bf16(kf, qfB[s], sB[nb], 0, 0, 0);
      }
    __builtin_amdgcn_s_setprio(0);

    float vA[16], vB[16];
#pragma unroll
    for (int nb = 0; nb < 4; ++nb)
#pragma unroll
      for (int r = 0; r < 4; ++r) {
        vA[nb * 4 + r] = sA[nb][r];
        vB[nb * 4 + r] = sB[nb][r];
      }
    if (kt == qtB) {
      int qg = wave * 16 + l15;
#pragma unroll
      for (int i = 0; i < 16; ++i) {
        int kg = (i >> 2) * 16 + l4 * 4 + (i & 3);
        if (kg > qg) vB[i] = -1e30f;
      }
    }
    float tA[8], tB[8];
#pragma unroll
    for (int i = 0; i < 8; ++i) {
      tA[i] = fmaxf(vA[2 * i], vA[2 * i + 1]);
      tB[i] = fmaxf(vB[2 * i], vB[2 * i + 1]);
    }
#pragma unroll
    for (int i = 0; i < 4; ++i) {
      tA[i] = fmaxf(tA[i], tA[i + 4]);
      tB[i] = fmaxf(tB[i], tB[i + 4]);
    }
    float mxA = fmaxf(fmaxf(tA[0], tA[2]), fmaxf(tA[1], tA[3]));
    float mxB = fmaxf(fmaxf(tB[0], tB[2]), fmaxf(tB[1], tB[3]));
    if (!__all(fmaxf(mxA - mA, mxB - mB) <= 8.0f)) {
      float mrA = fmaxf(mxA, __shfl_xor(mxA, 16));
      float mrB = fmaxf(mxB, __shfl_xor(mxB, 16));
      mrA = fmaxf(mrA, __shfl_xor(mrA, 32));
      mrB = fmaxf(mrB, __shfl_xor(mrB, 32));
      float mnA = fmaxf(mA, mrA), mnB = fmaxf(mB, mrB);
      float aA = ex2(mA - mnA), aB = ex2(mB - mnB);
      mA = mnA;
      mB = mnB;
      lsA *= aA;
      lsB *= aB;
#pragma unroll
      for (int hb = 0; hb < 4; ++hb)
#pragma unroll
        for (int r = 0; r < 4; ++r) {
          oA[hb][r] *= aA;
          oB[hb][r] *= aB;
        }
    }
    float pA[16], pB[16];
#pragma unroll
    for (int i = 0; i < 16; ++i) {
      pA[i] = ex2(vA[i] - mA);
      pB[i] = ex2(vB[i] - mB);
    }
    float uA[8], uB[8];
#pragma unroll
    for (int i = 0; i < 8; ++i) {
      uA[i] = pA[2 * i] + pA[2 * i + 1];
      uB[i] = pB[2 * i] + pB[2 * i + 1];
    }
#pragma unroll
    for (int i = 0; i < 4; ++i) {
      uA[i] += uA[i + 4];
      uB[i] += uB[i + 4];
    }
    lsA += (uA[0] + uA[2]) + (uA[1] + uA[3]);
    lsB += (uB[0] + uB[2]) + (uB[1] + uB[3]);
    bf16x8 pfA[2], pfB[2];
#pragma unroll
    for (int s = 0; s < 2; ++s) {
      u32x4 wa, wb;
      wa.x = cvt_pk_bf16(pA[8 * s + 0], pA[8 * s + 1]);
      wb.x = cvt_pk_bf16(pB[8 * s + 0], pB[8 * s + 1]);
      wa.y = cvt_pk_bf16(pA[8 * s + 2], pA[8 * s + 3]);
      wb.y = cvt_pk_bf16(pB[8 * s + 2], pB[8 * s + 3]);
      wa.z = cvt_pk_bf16(pA[8 * s + 4], pA[8 * s + 5]);
      wb.z = cvt_pk_bf16(pB[8 * s + 4], pB[8 * s + 5]);
      wa.w = cvt_pk_bf16(pA[8 * s + 6], pA[8 * s + 7]);
      wb.w = cvt_pk_bf16(pB[8 * s + 6], pB[8 * s + 7]);
      pfA[s] = __builtin_bit_cast(bf16x8, wa);
      pfB[s] = __builtin_bit_cast(bf16x8, wb);
    }
    bf16x8 vf[2][4];
#pragma unroll
    for (int s = 0; s < 2; ++s)
#pragma unroll
      for (int hb = 0; hb < 4; ++hb) {
        bf16x4 ta = tr16(&Vtr[cur][(hb * 16 + s * 8) * 64 + lane * 4]);
        bf16x4 tb = tr16(&Vtr[cur][(hb * 16 + s * 8 + 4) * 64 + lane * 4]);
        vf[s][hb] = __builtin_shufflevector(ta, tb, 0, 1, 2, 3, 4, 5, 6, 7);
      }
    asm volatile("s_waitcnt lgkmcnt(0)" ::: "memory");
    __builtin_amdgcn_sched_barrier(0);
    __builtin_amdgcn_s_setprio(1);
#pragma unroll
    for (int s = 0; s < 2; ++s)
#pragma unroll
      for (int hb = 0; hb < 4; ++hb) {
        oA[hb] = __builtin_amdgcn_mfma_f32_16x16x32_bf16(vf[s][hb], pfA[s], oA[hb], 0, 0, 0);
        oB[hb] = __builtin_amdgcn_mfma_f32_16x16x32_bf16(vf[s][hb], pfB[s], oB[hb], 0, 0, 0);
      }
    __builtin_amdgcn_s_setprio(0);

    // refill the buffer consumed last iteration (safe: its readers passed
    // this iteration's top barrier); clamp keeps 4 ops issued every slot
    int nt = kt + 3 > qtA ? qtA : kt + 3;
    stage((cur + 3) & 3, nt);
    cur = (cur + 1) & 3;
  }

  // ======== phase 2: A only (kt = qtB+1..qtA) ========
#pragma unroll 1
  for (; kt <= qtA; ++kt) {
    asm volatile("s_waitcnt vmcnt(8)" ::: "memory");
    __builtin_amdgcn_s_barrier();
    __builtin_amdgcn_sched_barrier(0);

    f32x4 sA[4] = {fz, fz, fz, fz};
    __builtin_amdgcn_s_setprio(1);
#pragma unroll
    for (int s = 0; s < 2; ++s)
#pragma unroll
      for (int nb = 0; nb < 4; ++nb) {
        int kk = nb * 16 + l15;
        int ch = (s * 4 + l4) ^ (kk & 7);
        bf16x8 kf = *(const bf16x8*)&Kl[cur][kk * 64 + ch * 8];
        sA[nb] = __builtin_amdgcn_mfma_f32_16x16x32_bf16(kf, qfA[s], sA[nb], 0, 0, 0);
      }
    __builtin_amdgcn_s_setprio(0);

    float vA[16];
#pragma unroll
    for (int nb = 0; nb < 4; ++nb)
#pragma unroll
      for (int r = 0; r < 4; ++r) vA[nb * 4 + r] = sA[nb][r];
    if (kt == qtA) {
      int qg = wave * 16 + l15;
#pragma unroll
      for (int i = 0; i < 16; ++i) {
        int kg = (i >> 2) * 16 + l4 * 4 + (i & 3);
        if (kg > qg) vA[i] = -1e30f;
      }
    }
    float tA[8];
#pragma unroll
    for (int i = 0; i < 8; ++i) tA[i] = fmaxf(vA[2 * i], vA[2 * i + 1]);
#pragma unroll
    for (int i = 0; i < 4; ++i) tA[i] = fmaxf(tA[i], tA[i + 4]);
    float mxA = fmaxf(fmaxf(tA[0], tA[2]), fmaxf(tA[1], tA[3]));
    if (!__all(mxA <= mA + 8.0f)) {
      float mrA = fmaxf(mxA, __shfl_xor(mxA, 16));
      mrA = fmaxf(mrA, __shfl_xor(mrA, 32));
      float mnA = fmaxf(mA, mrA);
      float aA = ex2(mA - mnA);
      mA = mnA;
      lsA *= aA;
#pragma unroll
      for (int hb = 0; hb < 4; ++hb)
#pragma unroll
        for (int r = 0; r < 4; ++r) oA[hb][r] *= aA;
    }
    float pA[16];
#pragma unroll
    for (int i = 0; i < 16; ++i) pA[i] = ex2(vA[i] - mA);
    float uA[8];
#pragma unroll
    for (int i = 0; i < 8; ++i) uA[i] = pA[2 * i] + pA[2 * i + 1];
#pragma unroll
    for (int i = 0; i < 4; ++i) uA[i] += uA[i + 4];
    lsA += (uA[0] + uA[2]) + (uA[1] + uA[3]);
    bf16x8 pfA[2];
#pragma unroll
    for (int s = 0; s < 2; ++s) {
      u32x4 wa;
      wa.x = cvt_pk_bf16(pA[8 * s + 0], pA[8 * s + 1]);
      wa.y = cvt_pk_bf16(pA[8 * s + 2], pA[8 * s + 3]);
      wa.z = cvt_pk_bf16(pA[8 * s + 4], pA[8 * s + 5]);
      wa.w = cvt_pk_bf16(pA[8 * s + 6], pA[8 * s + 7]);
      pfA[s] = __builtin_bit_cast(bf16x8, wa);
    }
    bf16x8 vf[2][4];
#pragma unroll
    for (int s = 0; s < 2; ++s)
#pragma unroll
      for (int hb = 0; hb < 4; ++hb) {
        bf16x4 ta = tr16(&Vtr[cur][(hb * 16 + s * 8) * 64 + lane * 4]);
        bf16x4 tb = tr16(&Vtr[cur][(hb * 16 + s * 8 + 4) * 64 + lane * 4]);
        vf[s][hb] = __builtin_shufflevector(ta, tb, 0, 1, 2, 3, 4, 5, 6, 7);
      }
    asm volatile("s_waitcnt lgkmcnt(0)" ::: "memory");
    __builtin_amdgcn_sched_barrier(0);
    __builtin_amdgcn_s_setprio(1);
#pragma unroll
    for (int s = 0; s < 2; ++s)
#pragma unroll
      for (int hb = 0; hb < 4; ++hb)
        oA[hb] = __builtin_amdgcn_mfma_f32_16x16x32_bf16(vf[s][hb], pfA[s], oA[hb], 0, 0, 0);
    __builtin_amdgcn_s_setprio(0);

    int nt = kt + 3 > qtA ? qtA : kt + 3;
    stage((cur + 3) & 3, nt);
    cur = (cur + 1) & 3;
  }

  // epilogue: merge group-partial lsum (2 shuffles), divide, store
  auto epi = [&](f32x4* accO, float lsum, int qt) {
    float t = lsum + __shfl_xor(lsum, 16);
    t += __shfl_xor(t, 32);
    float inv = 1.0f / t;
    int qg = qt * 64 + wave * 16 + l15;
    u16* yrow = Y + (size_t)(b * 2048 + qg) * 1024 + h * 64;
#pragma unroll
    for (int hb = 0; hb < 4; ++hb) {
      uint2 pk;
      pk.x = cvt_pk_bf16(accO[hb][0] * inv, accO[hb][1] * inv);
      pk.y = cvt_pk_bf16(accO[hb][2] * inv, accO[hb][3] * inv);
      *(uint2*)&yrow[hb * 16 + l4 * 4] = pk;
    }
  };
  epi(oA, lsA, qtA);
  epi(oB, lsB, qtB);
}

extern "C" void kernel_launch(void* const* d_in, const int* in_sizes, int n_in,
                              void* d_out, int out_size, void* d_ws, size_t ws_size,
                              hipStream_t stream) {
  const float* x = (const float*)d_in[0];       // [2,2048,1024]
  const float* Wqkv = (const float*)d_in[1];    // [1024,3072]
  const float* Wproj = (const float*)d_in[2];   // [1024,1024]
  float* out = (float*)d_out;                   // [2,2048,1024] f32

  char* ws = (char*)d_ws;
  u16* Xb  = (u16*)(ws + 0);                    // 8 MB  [4096][1024]
  u16* Wqt = (u16*)(ws + ((size_t)8 << 20));    // 6 MB  [3072][1024]
  u16* Wpt = (u16*)(ws + ((size_t)14 << 20));   // 2 MB  [1024][1024]
  u16* Qs  = (u16*)(ws + ((size_t)16 << 20));   // 8 MB  [2,16,2048,64]
  u16* Ks  = (u16*)(ws + ((size_t)24 << 20));   // 8 MB
  u16* Vs  = (u16*)(ws + ((size_t)32 << 20));   // 8 MB
  u16* Yb  = (u16*)(ws + ((size_t)40 << 20));   // 8 MB  [4096][1024]

  k_cast<<<2048, 256, 0, stream>>>(x, Xb, 4096 * 1024 / 8);
  k_tcast<<<dim3(96, 32), 256, 0, stream>>>(Wqkv, Wqt, 1024, 3072);
  k_tcast<<<dim3(32, 32), 256, 0, stream>>>(Wproj, Wpt, 1024, 1024);
  k_gemm<0><<<dim3(24, 32), 256, 0, stream>>>(Xb, Wqt, Qs, Ks, Vs, nullptr, 1024);
  k_attn<<<dim3(16, 32), 256, 0, stream>>>(Qs, Ks, Vs, Yb);
  k_gemm<1><<<dim3(8, 32), 256, 0, stream>>>(Yb, Wpt, nullptr, nullptr, nullptr, out, 1024);
}

// Round 15
// 106.783 us; speedup vs baseline: 2.0626x; 1.0290x over previous
//
#include <hip/hip_runtime.h>

typedef __bf16 bf16x8 __attribute__((ext_vector_type(8)));
typedef __bf16 bf16x4 __attribute__((ext_vector_type(4)));
typedef float f32x4 __attribute__((ext_vector_type(4)));
typedef unsigned short u16;
typedef unsigned int u32;
typedef u32 u32x4 __attribute__((ext_vector_type(4)));

__device__ __forceinline__ u16 f2bf(float f) {
  u32 u = __builtin_bit_cast(u32, f);
  u += 0x7fffu + ((u >> 16) & 1u);
  return (u16)(u >> 16);
}

__device__ __forceinline__ u32 cvt_pk_bf16(float lo, float hi) {
  u32 r;
  asm("v_cvt_pk_bf16_f32 %0, %1, %2" : "=v"(r) : "v"(lo), "v"(hi));
  return r;
}

__device__ __forceinline__ float ex2(float x) {
  float r;
  asm("v_exp_f32 %0, %1" : "=v"(r) : "v"(x));
  return r;
}

__device__ __forceinline__ void gl_lds16(const u16* g, u16* l) {
  __builtin_amdgcn_global_load_lds(
      (const __attribute__((address_space(1))) u32*)g,
      (__attribute__((address_space(3))) u32*)l, 16, 0, 0);
}

// LDS transpose read; per-lane address p = base + lane*4 elems (verified R4).
__device__ __forceinline__ bf16x4 tr16(const u16* p) {
  bf16x4 r;
  auto lp = (const __attribute__((address_space(3))) u16*)p;
  asm volatile("ds_read_b64_tr_b16 %0, %1" : "=&v"(r) : "v"(lp));
  return r;
}

// ---------------- cast x: f32 -> bf16, 8 elems/thread ----------------
__global__ __launch_bounds__(256) void k_cast(const float* __restrict__ in,
                                              u16* __restrict__ out, int n8) {
  int i = blockIdx.x * 256 + threadIdx.x;
  if (i >= n8) return;
  const float4* p = (const float4*)in + (size_t)i * 2;
  float4 a = p[0], b = p[1];
  u16 r[8] = {f2bf(a.x), f2bf(a.y), f2bf(a.z), f2bf(a.w),
              f2bf(b.x), f2bf(b.y), f2bf(b.z), f2bf(b.w)};
  ((uint4*)out)[i] = *(const uint4*)r;
}

// ---------- transpose+cast: W [K][N] f32 -> Wt [N][K] bf16 ----------
__global__ __launch_bounds__(256) void k_tcast(const float* __restrict__ in,
                                               u16* __restrict__ out, int K, int N) {
  __shared__ float tile[32][33];
  int n0 = blockIdx.x * 32, k0 = blockIdx.y * 32;
  int c = threadIdx.x & 31, r0 = (threadIdx.x >> 5) * 4;
#pragma unroll
  for (int rr = 0; rr < 4; ++rr) {
    int r = r0 + rr;
    tile[r][c] = in[(size_t)(k0 + r) * N + n0 + c];
  }
  __syncthreads();
#pragma unroll
  for (int rr = 0; rr < 4; ++rr) {
    int r = r0 + rr;
    out[(size_t)(n0 + r) * K + k0 + c] = f2bf(tile[c][r]);
  }
}

// ---------------- bf16 GEMM (R13-verified): BK=64, LDS union, 4 blk/CU ------
template <int EPI>
__global__ __launch_bounds__(256) void k_gemm(const u16* __restrict__ A,
                                              const u16* __restrict__ Bt,
                                              u16* __restrict__ Qp, u16* __restrict__ Kp,
                                              u16* __restrict__ Vp, float* __restrict__ Cf,
                                              int K) {
  __shared__ char smem[128 * 136 * 2];  // 34.8 KB
  u16* As = (u16*)smem;                 // [128][64] (loop)
  u16* Bs = (u16*)(smem + 16384);       // [128][64] (loop)
  u16* Cs = (u16*)smem;                 // [128][136] (epilogue)
  const int tid = threadIdx.x;
  const int lane = tid & 63, wave = tid >> 6;
  const int l15 = lane & 15, l4 = lane >> 4;
  const int wr = wave >> 1, wc = wave & 1;
  const int tm = blockIdx.y, tn = blockIdx.x;

  int srow[4], scol[4];
#pragma unroll
  for (int i = 0; i < 4; ++i) {
    srow[i] = wave * 32 + i * 8 + (lane >> 3);
    scol[i] = ((lane & 7) ^ (srow[i] & 7)) * 8;
  }

  const f32x4 fz = {0.f, 0.f, 0.f, 0.f};
  f32x4 acc[4][4];
#pragma unroll
  for (int a = 0; a < 4; ++a)
#pragma unroll
    for (int b = 0; b < 4; ++b) acc[a][b] = fz;

  const int nk = K >> 6;
  for (int kt = 0; kt < nk; ++kt) {
#pragma unroll
    for (int i = 0; i < 4; ++i)
      gl_lds16(A + (size_t)(tm * 128 + srow[i]) * K + kt * 64 + scol[i],
               &As[(wave * 4 + i) * 512]);
#pragma unroll
    for (int i = 0; i < 4; ++i)
      gl_lds16(Bt + (size_t)(tn * 128 + srow[i]) * K + kt * 64 + scol[i],
               &Bs[(wave * 4 + i) * 512]);
    __syncthreads();
    bf16x8 af[2][4], bfr[2][4];
#pragma unroll
    for (int s = 0; s < 2; ++s) {
#pragma unroll
      for (int mi = 0; mi < 4; ++mi) {
        int row = wr * 64 + mi * 16 + l15;
        int pch = (s * 4 + l4) ^ (row & 7);
        af[s][mi] = *(const bf16x8*)&As[row * 64 + pch * 8];
      }
#pragma unroll
      for (int ni = 0; ni < 4; ++ni) {
        int row = wc * 64 + ni * 16 + l15;
        int pch = (s * 4 + l4) ^ (row & 7);
        bfr[s][ni] = *(const bf16x8*)&Bs[row * 64 + pch * 8];
      }
    }
    __builtin_amdgcn_s_setprio(1);
#pragma unroll
    for (int s = 0; s < 2; ++s)
#pragma unroll
      for (int mi = 0; mi < 4; ++mi)
#pragma unroll
        for (int ni = 0; ni < 4; ++ni)
          acc[mi][ni] = __builtin_amdgcn_mfma_f32_16x16x32_bf16(af[s][mi], bfr[s][ni],
                                                                acc[mi][ni], 0, 0, 0);
    __builtin_amdgcn_s_setprio(0);
    __syncthreads();
  }

  if (EPI == 0) {
#pragma unroll
    for (int ni = 0; ni < 4; ++ni) {
      int colb = wc * 64 + ni * 16;
      float scl = ((tn * 128 + colb) >> 10) == 0 ? 0.180336880f : 1.0f;  // 0.125*log2e
#pragma unroll
      for (int mi = 0; mi < 4; ++mi)
#pragma unroll
        for (int r = 0; r < 4; ++r) {
          int rowb = wr * 64 + mi * 16 + l4 * 4 + r;
          Cs[rowb * 136 + colb + l15] = f2bf(acc[mi][ni][r] * scl);
        }
    }
    __syncthreads();
#pragma unroll
    for (int pass = 0; pass < 8; ++pass) {
      int rowb = pass * 16 + (tid >> 4);
      int colb = (tid & 15) * 8;
      uint4 v = *(const uint4*)&Cs[rowb * 136 + colb];
      int rowg = tm * 128 + rowb;
      int b = rowg >> 11, t = rowg & 2047;
      int gcol = tn * 128 + colb;
      int which = gcol >> 10;
      int d = gcol & 1023;
      int h = d >> 6, hd = d & 63;
      u16* dst = which == 0 ? Qp : (which == 1 ? Kp : Vp);
      *(uint4*)&dst[(size_t)(((b * 16 + h) * 2048 + t) * 64 + hd)] = v;
    }
  } else {
    const int rbase = tm * 128 + wr * 64 + l4 * 4;
    const int cbase = tn * 128 + wc * 64 + l15;
#pragma unroll
    for (int mi = 0; mi < 4; ++mi)
#pragma unroll
      for (int r = 0; r < 4; ++r) {
        int rowg = rbase + mi * 16 + r;
#pragma unroll
        for (int ni = 0; ni < 4; ++ni)
          Cf[(size_t)rowg * 1024 + cbase + ni * 16] = acc[mi][ni][r];
      }
  }
}

// ---------------- causal flash attention (v11b: slot-balanced, RACE FIXED) ----
// 17 slots/block. Phase 1 (kt=0..qtB): A+B, one tile/slot, 1 barrier/slot
// (stage targets buffer consumed at kt-1 -- proven R13).
// Phase 2: A-only, TWO tiles/slot. RACE FIX vs R14: a second barrier between
// the PV reads and the same-slot restage (other waves may still be reading).
__global__ __launch_bounds__(256) void k_attn(const u16* __restrict__ Q,
                                              const u16* __restrict__ K,
                                              const u16* __restrict__ V,
                                              u16* __restrict__ Y) {
  __shared__ u16 Kl[4][64 * 64];   // [kk][hd], chunk ^= kk&7
  __shared__ u16 Vtr[4][64 * 64];  // subtiled
  const int tid = threadIdx.x, lane = tid & 63, wave = tid >> 6;
  const int l15 = lane & 15, l4 = lane >> 4;
  const int bh = blockIdx.y;
  const int pp = (blockIdx.x + ((blockIdx.y >> 4) << 3)) & 15;
  const int qtA = 31 - pp, qtB = pp;  // qtB < qtA
  const u16* Qb = Q + (size_t)bh * 2048 * 64;
  const u16* Kb = K + (size_t)bh * 2048 * 64;
  const u16* Vb = V + (size_t)bh * 2048 * 64;
  const int b = bh >> 4, h = bh & 15;
  const f32x4 fz = {0.f, 0.f, 0.f, 0.f};

  const int kk0 = wave * 16 + (lane >> 3);
  const int kk1 = kk0 + 8;
  const int lcol0 = ((lane & 7) ^ (kk0 & 7)) * 8;
  const int lcol1 = ((lane & 7) ^ (kk1 & 7)) * 8;
  int vk[2], vhd[2];
#pragma unroll
  for (int i = 0; i < 2; ++i) {
    int o = (wave * 2 + i) * 512 + lane * 8;
    vk[i] = ((o >> 6) & 15) * 4 + ((o >> 4) & 3);
    vhd[i] = ((o >> 10) << 4) + (o & 8);
  }

  auto stage = [&](int buf, int kt) {
    gl_lds16(Kb + (size_t)(kt * 64 + kk0) * 64 + lcol0, &Kl[buf][(wave * 2 + 0) * 512]);
    gl_lds16(Kb + (size_t)(kt * 64 + kk1) * 64 + lcol1, &Kl[buf][(wave * 2 + 1) * 512]);
    gl_lds16(Vb + (size_t)(kt * 64 + vk[0]) * 64 + vhd[0], &Vtr[buf][(wave * 2 + 0) * 512]);
    gl_lds16(Vb + (size_t)(kt * 64 + vk[1]) * 64 + vhd[1], &Vtr[buf][(wave * 2 + 1) * 512]);
  };

  auto qk = [&](int buf, const bf16x8* qf, f32x4* accS) {
#pragma unroll
    for (int s = 0; s < 2; ++s)
#pragma unroll
      for (int nb = 0; nb < 4; ++nb) {
        int kk = nb * 16 + l15;
        int ch = (s * 4 + l4) ^ (kk & 7);
        bf16x8 kf = *(const bf16x8*)&Kl[buf][kk * 64 + ch * 8];
        accS[nb] = __builtin_amdgcn_mfma_f32_16x16x32_bf16(kf, qf[s], accS[nb], 0, 0, 0);
      }
  };
  auto pv = [&](int buf, const bf16x8* pf, f32x4* accO) {
#pragma unroll
    for (int s = 0; s < 2; ++s) {
      bf16x8 vf[4];
#pragma unroll
      for (int hb = 0; hb < 4; ++hb) {
        bf16x4 ta = tr16(&Vtr[buf][(hb * 16 + s * 8) * 64 + lane * 4]);
        bf16x4 tb = tr16(&Vtr[buf][(hb * 16 + s * 8 + 4) * 64 + lane * 4]);
        vf[hb] = __builtin_shufflevector(ta, tb, 0, 1, 2, 3, 4, 5, 6, 7);
      }
      asm volatile("s_waitcnt lgkmcnt(0)" ::: "memory");
      __builtin_amdgcn_sched_barrier(0);
      __builtin_amdgcn_s_setprio(1);
#pragma unroll
      for (int hb = 0; hb < 4; ++hb)
        accO[hb] = __builtin_amdgcn_mfma_f32_16x16x32_bf16(vf[hb], pf[s], accO[hb], 0, 0, 0);
      __builtin_amdgcn_s_setprio(0);
    }
  };

  bf16x8 qfA[2], qfB[2];
  {
    int qrA = qtA * 64 + wave * 16 + l15;
    int qrB = qtB * 64 + wave * 16 + l15;
    qfA[0] = *(const bf16x8*)&Qb[(size_t)qrA * 64 + l4 * 8];
    qfA[1] = *(const bf16x8*)&Qb[(size_t)qrA * 64 + 32 + l4 * 8];
    qfB[0] = *(const bf16x8*)&Qb[(size_t)qrB * 64 + l4 * 8];
    qfB[1] = *(const bf16x8*)&Qb[(size_t)qrB * 64 + 32 + l4 * 8];
  }
  f32x4 oA[4] = {fz, fz, fz, fz}, oB[4] = {fz, fz, fz, fz};
  float mA = -1e30f, lsA = 0.f, mB = -1e30f, lsB = 0.f;

  // ======== phase 1: A+B on tiles 0..qtB (1 barrier/slot, proven R13) ========
  stage(0, 0);
  stage(1, 1);
  stage(2, 2);
  int cur = 0;
#pragma unroll 1
  for (int kt = 0; kt <= qtB; ++kt) {
    asm volatile("s_waitcnt vmcnt(8)" ::: "memory");
    __builtin_amdgcn_s_barrier();
    __builtin_amdgcn_sched_barrier(0);

    f32x4 sA[4] = {fz, fz, fz, fz}, sB[4] = {fz, fz, fz, fz};
    __builtin_amdgcn_s_setprio(1);
#pragma unroll
    for (int s = 0; s < 2; ++s)
#pragma unroll
      for (int nb = 0; nb < 4; ++nb) {
        int kk = nb * 16 + l15;
        int ch = (s * 4 + l4) ^ (kk & 7);
        bf16x8 kf = *(const bf16x8*)&Kl[cur][kk * 64 + ch * 8];
        sA[nb] = __builtin_amdgcn_mfma_f32_16x16x32_bf16(kf, qfA[s], sA[nb], 0, 0, 0);
        sB[nb] = __builtin_amdgcn_mfma_f32_16x16x32_bf16(kf, qfB[s], sB[nb], 0, 0, 0);
      }
    __builtin_amdgcn_s_setprio(0);

    float vA[16], vB[16];
#pragma unroll
    for (int nb = 0; nb < 4; ++nb)
#pragma unroll
      for (int r = 0; r < 4; ++r) {
        vA[nb * 4 + r] = sA[nb][r];
        vB[nb * 4 + r] = sB[nb][r];
      }
    if (kt == qtB) {
      int qg = wave * 16 + l15;
#pragma unroll
      for (int i = 0; i < 16; ++i) {
        int kg = (i >> 2) * 16 + l4 * 4 + (i & 3);
        if (kg > qg) vB[i] = -1e30f;
      }
    }
    float tA[8], tB[8];
#pragma unroll
    for (int i = 0; i < 8; ++i) {
      tA[i] = fmaxf(vA[2 * i], vA[2 * i + 1]);
      tB[i] = fmaxf(vB[2 * i], vB[2 * i + 1]);
    }
#pragma unroll
    for (int i = 0; i < 4; ++i) {
      tA[i] = fmaxf(tA[i], tA[i + 4]);
      tB[i] = fmaxf(tB[i], tB[i + 4]);
    }
    float mxA = fmaxf(fmaxf(tA[0], tA[2]), fmaxf(tA[1], tA[3]));
    float mxB = fmaxf(fmaxf(tB[0], tB[2]), fmaxf(tB[1], tB[3]));
    if (!__all(fmaxf(mxA - mA, mxB - mB) <= 8.0f)) {
      float mrA = fmaxf(mxA, __shfl_xor(mxA, 16));
      float mrB = fmaxf(mxB, __shfl_xor(mxB, 16));
      mrA = fmaxf(mrA, __shfl_xor(mrA, 32));
      mrB = fmaxf(mrB, __shfl_xor(mrB, 32));
      float mnA = fmaxf(mA, mrA), mnB = fmaxf(mB, mrB);
      float aA = ex2(mA - mnA), aB = ex2(mB - mnB);
      mA = mnA;
      mB = mnB;
      lsA *= aA;
      lsB *= aB;
#pragma unroll
      for (int hb = 0; hb < 4; ++hb)
#pragma unroll
        for (int r = 0; r < 4; ++r) {
          oA[hb][r] *= aA;
          oB[hb][r] *= aB;
        }
    }
    float pA[16], pB[16];
#pragma unroll
    for (int i = 0; i < 16; ++i) {
      pA[i] = ex2(vA[i] - mA);
      pB[i] = ex2(vB[i] - mB);
    }
    float uA[8], uB[8];
#pragma unroll
    for (int i = 0; i < 8; ++i) {
      uA[i] = pA[2 * i] + pA[2 * i + 1];
      uB[i] = pB[2 * i] + pB[2 * i + 1];
    }
#pragma unroll
    for (int i = 0; i < 4; ++i) {
      uA[i] += uA[i + 4];
      uB[i] += uB[i + 4];
    }
    lsA += (uA[0] + uA[2]) + (uA[1] + uA[3]);
    lsB += (uB[0] + uB[2]) + (uB[1] + uB[3]);
    bf16x8 pfA[2], pfB[2];
#pragma unroll
    for (int s = 0; s < 2; ++s) {
      u32x4 wa, wb;
      wa.x = cvt_pk_bf16(pA[8 * s + 0], pA[8 * s + 1]);
      wb.x = cvt_pk_bf16(pB[8 * s + 0], pB[8 * s + 1]);
      wa.y = cvt_pk_bf16(pA[8 * s + 2], pA[8 * s + 3]);
      wb.y = cvt_pk_bf16(pB[8 * s + 2], pB[8 * s + 3]);
      wa.z = cvt_pk_bf16(pA[8 * s + 4], pA[8 * s + 5]);
      wb.z = cvt_pk_bf16(pB[8 * s + 4], pB[8 * s + 5]);
      wa.w = cvt_pk_bf16(pA[8 * s + 6], pA[8 * s + 7]);
      wb.w = cvt_pk_bf16(pB[8 * s + 6], pB[8 * s + 7]);
      pfA[s] = __builtin_bit_cast(bf16x8, wa);
      pfB[s] = __builtin_bit_cast(bf16x8, wb);
    }
#pragma unroll
    for (int s = 0; s < 2; ++s) {
      bf16x8 vf[4];
#pragma unroll
      for (int hb = 0; hb < 4; ++hb) {
        bf16x4 ta = tr16(&Vtr[cur][(hb * 16 + s * 8) * 64 + lane * 4]);
        bf16x4 tb = tr16(&Vtr[cur][(hb * 16 + s * 8 + 4) * 64 + lane * 4]);
        vf[hb] = __builtin_shufflevector(ta, tb, 0, 1, 2, 3, 4, 5, 6, 7);
      }
      asm volatile("s_waitcnt lgkmcnt(0)" ::: "memory");
      __builtin_amdgcn_sched_barrier(0);
      __builtin_amdgcn_s_setprio(1);
#pragma unroll
      for (int hb = 0; hb < 4; ++hb) {
        oA[hb] = __builtin_amdgcn_mfma_f32_16x16x32_bf16(vf[hb], pfA[s], oA[hb], 0, 0, 0);
        oB[hb] = __builtin_amdgcn_mfma_f32_16x16x32_bf16(vf[hb], pfB[s], oB[hb], 0, 0, 0);
      }
      __builtin_amdgcn_s_setprio(0);
    }

    int nt = kt + 3 > qtB ? qtB : kt + 3;  // clamp to phase-1 range
    stage((cur + 3) & 3, nt);
    cur = (cur + 1) & 3;
  }

  // ======== phase 2: A-only, TWO tiles per slot (2 barriers/slot) ========
  const int t0 = qtB + 1;
  const int rem = qtA - qtB;           // odd, >= 1
  const int nd = (rem - 1) >> 1;       // dual slots
  __builtin_amdgcn_s_barrier();        // all waves done reading phase-1 bufs
  __builtin_amdgcn_sched_barrier(0);
#pragma unroll
  for (int i = 0; i < 4; ++i) {
    int tt = t0 + i > qtA ? qtA : t0 + i;
    stage(i, tt);
  }

  auto smx2 = [&](f32x4* s1, f32x4* s2, bf16x8* pf1, bf16x8* pf2) {
    float v1[16], v2[16];
#pragma unroll
    for (int nb = 0; nb < 4; ++nb)
#pragma unroll
      for (int r = 0; r < 4; ++r) {
        v1[nb * 4 + r] = s1[nb][r];
        v2[nb * 4 + r] = s2[nb][r];
      }
    float t1[8], t2[8];
#pragma unroll
    for (int i = 0; i < 8; ++i) {
      t1[i] = fmaxf(v1[2 * i], v1[2 * i + 1]);
      t2[i] = fmaxf(v2[2 * i], v2[2 * i + 1]);
    }
#pragma unroll
    for (int i = 0; i < 4; ++i) {
      t1[i] = fmaxf(t1[i], t1[i + 4]);
      t2[i] = fmaxf(t2[i], t2[i + 4]);
    }
    float mx = fmaxf(fmaxf(fmaxf(t1[0], t1[2]), fmaxf(t1[1], t1[3])),
                     fmaxf(fmaxf(t2[0], t2[2]), fmaxf(t2[1], t2[3])));
    if (!__all(mx <= mA + 8.0f)) {
      float mr = fmaxf(mx, __shfl_xor(mx, 16));
      mr = fmaxf(mr, __shfl_xor(mr, 32));
      float mn = fmaxf(mA, mr);
      float a = ex2(mA - mn);
      mA = mn;
      lsA *= a;
#pragma unroll
      for (int hb = 0; hb < 4; ++hb)
#pragma unroll
        for (int r = 0; r < 4; ++r) oA[hb][r] *= a;
    }
    float p1[16], p2[16];
#pragma unroll
    for (int i = 0; i < 16; ++i) {
      p1[i] = ex2(v1[i] - mA);
      p2[i] = ex2(v2[i] - mA);
    }
    float u1[8], u2[8];
#pragma unroll
    for (int i = 0; i < 8; ++i) {
      u1[i] = p1[2 * i] + p1[2 * i + 1];
      u2[i] = p2[2 * i] + p2[2 * i + 1];
    }
#pragma unroll
    for (int i = 0; i < 4; ++i) {
      u1[i] += u1[i + 4];
      u2[i] += u2[i + 4];
    }
    lsA += (u1[0] + u1[2]) + (u1[1] + u1[3]) + (u2[0] + u2[2]) + (u2[1] + u2[3]);
#pragma unroll
    for (int s = 0; s < 2; ++s) {
      u32x4 w1, w2;
      w1.x = cvt_pk_bf16(p1[8 * s + 0], p1[8 * s + 1]);
      w2.x = cvt_pk_bf16(p2[8 * s + 0], p2[8 * s + 1]);
      w1.y = cvt_pk_bf16(p1[8 * s + 2], p1[8 * s + 3]);
      w2.y = cvt_pk_bf16(p2[8 * s + 2], p2[8 * s + 3]);
      w1.z = cvt_pk_bf16(p1[8 * s + 4], p1[8 * s + 5]);
      w2.z = cvt_pk_bf16(p2[8 * s + 4], p2[8 * s + 5]);
      w1.w = cvt_pk_bf16(p1[8 * s + 6], p1[8 * s + 7]);
      w2.w = cvt_pk_bf16(p2[8 * s + 6], p2[8 * s + 7]);
      pf1[s] = __builtin_bit_cast(bf16x8, w1);
      pf2[s] = __builtin_bit_cast(bf16x8, w2);
    }
  };

#pragma unroll 1
  for (int j = 0; j < nd; ++j) {
    asm volatile("s_waitcnt vmcnt(8)" ::: "memory");
    __builtin_amdgcn_s_barrier();
    __builtin_amdgcn_sched_barrier(0);
    int b0 = (2 * j) & 3, b1 = (2 * j + 1) & 3;

    f32x4 s1[4] = {fz, fz, fz, fz}, s2[4] = {fz, fz, fz, fz};
    __builtin_amdgcn_s_setprio(1);
    qk(b0, qfA, s1);
    qk(b1, qfA, s2);
    __builtin_amdgcn_s_setprio(0);
    bf16x8 pf1[2], pf2[2];
    smx2(s1, s2, pf1, pf2);
    pv(b0, pf1, oA);
    pv(b1, pf2, oA);

    // RACE FIX: other waves may still be reading b0/b1 -- barrier before restage
    __builtin_amdgcn_s_barrier();
    __builtin_amdgcn_sched_barrier(0);
    int ta = t0 + 2 * j + 4, tb2 = t0 + 2 * j + 5;
    stage(b0, ta > qtA ? qtA : ta);
    stage(b1, tb2 > qtA ? qtA : tb2);
  }

  // tail: single tile qtA (diagonal), buf (rem-1)&3
  {
    asm volatile("s_waitcnt vmcnt(8)" ::: "memory");
    __builtin_amdgcn_s_barrier();
    __builtin_amdgcn_sched_barrier(0);
    int buf = (rem - 1) & 3;
    f32x4 sA[4] = {fz, fz, fz, fz};
    __builtin_amdgcn_s_setprio(1);
    qk(buf, qfA, sA);
    __builtin_amdgcn_s_setprio(0);
    float vA[16];
#pragma unroll
    for (int nb = 0; nb < 4; ++nb)
#pragma unroll
      for (int r = 0; r < 4; ++r) vA[nb * 4 + r] = sA[nb][r];
    int qg = wave * 16 + l15;
#pragma unroll
    for (int i = 0; i < 16; ++i) {
      int kg = (i >> 2) * 16 + l4 * 4 + (i & 3);
      if (kg > qg) vA[i] = -1e30f;
    }
    float tA[8];
#pragma unroll
    for (int i = 0; i < 8; ++i) tA[i] = fmaxf(vA[2 * i], vA[2 * i + 1]);
#pragma unroll
    for (int i = 0; i < 4; ++i) tA[i] = fmaxf(tA[i], tA[i + 4]);
    float mxA = fmaxf(fmaxf(tA[0], tA[2]), fmaxf(tA[1], tA[3]));
    if (!__all(mxA <= mA + 8.0f)) {
      float mrA = fmaxf(mxA, __shfl_xor(mxA, 16));
      mrA = fmaxf(mrA, __shfl_xor(mrA, 32));
      float mnA = fmaxf(mA, mrA);
      float aA = ex2(mA - mnA);
      mA = mnA;
      lsA *= aA;
#pragma unroll
      for (int hb = 0; hb < 4; ++hb)
#pragma unroll
        for (int r = 0; r < 4; ++r) oA[hb][r] *= aA;
    }
    float pA[16];
#pragma unroll
    for (int i = 0; i < 16; ++i) pA[i] = ex2(vA[i] - mA);
    float uA[8];
#pragma unroll
    for (int i = 0; i < 8; ++i) uA[i] = pA[2 * i] + pA[2 * i + 1];
#pragma unroll
    for (int i = 0; i < 4; ++i) uA[i] += uA[i + 4];
    lsA += (uA[0] + uA[2]) + (uA[1] + uA[3]);
    bf16x8 pfA[2];
#pragma unroll
    for (int s = 0; s < 2; ++s) {
      u32x4 wa;
      wa.x = cvt_pk_bf16(pA[8 * s + 0], pA[8 * s + 1]);
      wa.y = cvt_pk_bf16(pA[8 * s + 2], pA[8 * s + 3]);
      wa.z = cvt_pk_bf16(pA[8 * s + 4], pA[8 * s + 5]);
      wa.w = cvt_pk_bf16(pA[8 * s + 6], pA[8 * s + 7]);
      pfA[s] = __builtin_bit_cast(bf16x8, wa);
    }
    pv(buf, pfA, oA);
  }

  // epilogue: merge group-partial lsum (2 shuffles), divide, store
  auto epi = [&](f32x4* accO, float lsum, int qt) {
    float t = lsum + __shfl_xor(lsum, 16);
    t += __shfl_xor(t, 32);
    float inv = 1.0f / t;
    int qg = qt * 64 + wave * 16 + l15;
    u16* yrow = Y + (size_t)(b * 2048 + qg) * 1024 + h * 64;
#pragma unroll
    for (int hb = 0; hb < 4; ++hb) {
      uint2 pk;
      pk.x = cvt_pk_bf16(accO[hb][0] * inv, accO[hb][1] * inv);
      pk.y = cvt_pk_bf16(accO[hb][2] * inv, accO[hb][3] * inv);
      *(uint2*)&yrow[hb * 16 + l4 * 4] = pk;
    }
  };
  epi(oA, lsA, qtA);
  epi(oB, lsB, qtB);
}

extern "C" void kernel_launch(void* const* d_in, const int* in_sizes, int n_in,
                              void* d_out, int out_size, void* d_ws, size_t ws_size,
                              hipStream_t stream) {
  const float* x = (const float*)d_in[0];       // [2,2048,1024]
  const float* Wqkv = (const float*)d_in[1];    // [1024,3072]
  const float* Wproj = (const float*)d_in[2];   // [1024,1024]
  float* out = (float*)d_out;                   // [2,2048,1024] f32

  char* ws = (char*)d_ws;
  u16* Xb  = (u16*)(ws + 0);                    // 8 MB  [4096][1024]
  u16* Wqt = (u16*)(ws + ((size_t)8 << 20));    // 6 MB  [3072][1024]
  u16* Wpt = (u16*)(ws + ((size_t)14 << 20));   // 2 MB  [1024][1024]
  u16* Qs  = (u16*)(ws + ((size_t)16 << 20));   // 8 MB  [2,16,2048,64]
  u16* Ks  = (u16*)(ws + ((size_t)24 << 20));   // 8 MB
  u16* Vs  = (u16*)(ws + ((size_t)32 << 20));   // 8 MB
  u16* Yb  = (u16*)(ws + ((size_t)40 << 20));   // 8 MB  [4096][1024]

  k_cast<<<2048, 256, 0, stream>>>(x, Xb, 4096 * 1024 / 8);
  k_tcast<<<dim3(96, 32), 256, 0, stream>>>(Wqkv, Wqt, 1024, 3072);
  k_tcast<<<dim3(32, 32), 256, 0, stream>>>(Wproj, Wpt, 1024, 1024);
  k_gemm<0><<<dim3(24, 32), 256, 0, stream>>>(Xb, Wqt, Qs, Ks, Vs, nullptr, 1024);
  k_attn<<<dim3(16, 32), 256, 0, stream>>>(Qs, Ks, Vs, Yb);
  k_gemm<1><<<dim3(8, 32), 256, 0, stream>>>(Yb, Wpt, nullptr, nullptr, nullptr, out, 1024);
}